// Round 1
// baseline (1819.497 us; speedup 1.0000x reference)
//
#include <hip/hip_runtime.h>
#include <math.h>

#define H   128
#define NR  6
#define NOUT 64

__device__ __forceinline__ float swishf(float z) {
  // z * sigmoid(z) = z / (1 + exp(-z)); safe at |z| huge: exp->inf => 0, exp->0 => z
  float t = __expf(-z);
  return z / (1.0f + t);
}

// ---------------- zero fill (float4) ----------------
__global__ void k_zero4(float4* __restrict__ p, int n4) {
  int i = blockIdx.x * blockDim.x + threadIdx.x;
  if (i < n4) p[i] = make_float4(0.f, 0.f, 0.f, 0.f);
}

// ---------------- tiny transpose: out[c][r] = in[r][c] ----------------
__global__ void k_transpose(const float* __restrict__ in, float* __restrict__ out,
                            int rows, int cols) {
  int idx = blockIdx.x * blockDim.x + threadIdx.x;
  if (idx >= rows * cols) return;
  int r = idx / cols, c = idx % cols;
  out[c * rows + r] = in[idx];
}

// ---------------- per-edge Bessel-RBF with envelope ----------------
__global__ void k_rbf(const float* __restrict__ pos, const int* __restrict__ src,
                      const int* __restrict__ dst, const float* __restrict__ freq,
                      float* __restrict__ rbf, int E) {
  int e = blockIdx.x * blockDim.x + threadIdx.x;
  if (e >= E) return;
  int s = src[e], d = dst[e];
  float dx = pos[d * 3 + 0] - pos[s * 3 + 0];
  float dy = pos[d * 3 + 1] - pos[s * 3 + 1];
  float dz = pos[d * 3 + 2] - pos[s * 3 + 2];
  float dist = sqrtf(dx * dx + dy * dy + dz * dz);
  float dn = dist * 0.2f;                       // d / CUTOFF
  float inv = 1.0f / dn;
  float dn2 = dn * dn;
  float dp = dn2 * dn2 * dn;                    // dn^5 (p=5)
  // A=-21, B=35, C=-15
  float env = inv - 21.0f * dp + 35.0f * dp * dn - 15.0f * dp * dn2;
  float fr[NR];
#pragma unroll
  for (int r = 0; r < NR; ++r) fr[r] = freq[r];
#pragma unroll
  for (int r = 0; r < NR; ++r)
    rbf[(size_t)e * NR + r] = env * sinf(fr[r] * dn);
}

// ---------------- triplet angles ----------------
__global__ void k_angle(const float* __restrict__ pos, const int* __restrict__ ii,
                        const int* __restrict__ jj, const int* __restrict__ kk,
                        float* __restrict__ out, int T) {
  int t = blockIdx.x * blockDim.x + threadIdx.x;
  if (t >= T) return;
  int i = ii[t], j = jj[t], k = kk[t];
  float pix = pos[i * 3], piy = pos[i * 3 + 1], piz = pos[i * 3 + 2];
  float vjx = pos[j * 3] - pix, vjy = pos[j * 3 + 1] - piy, vjz = pos[j * 3 + 2] - piz;
  float vkx = pos[k * 3] - pix, vky = pos[k * 3 + 1] - piy, vkz = pos[k * 3 + 2] - piz;
  float a = vjx * vkx + vjy * vky + vjz * vkz;
  float cx = vjy * vkz - vjz * vky;
  float cy = vjz * vkx - vjx * vkz;
  float cz = vjx * vky - vjy * vkx;
  float b = sqrtf(cx * cx + cy * cy + cz * cz);
  out[t] = atan2f(b, a);
}

// ---------------- generic NT fp32 GEMM: C = act(A[M,128] @ BT[128,NT] + bias) ----------------
template <int NT, bool SWISH, bool BIAS>
__global__ __launch_bounds__(256) void k_gemm_nt(
    const float* __restrict__ A,    // [M,128]
    const float* __restrict__ BT,   // [128][NT]  (pre-transposed weights)
    const float* __restrict__ bias, // [NT] or null
    float* __restrict__ C,          // [M,NT]
    int M) {
  constexpr int K = 128, MT = 64, KC = 64;
  constexpr int CPT = NT / 16; // cols per thread (8 or 4)
  __shared__ alignas(16) float As[KC][68];  // k-major, padded (16B-aligned rows)
  __shared__ alignas(16) float Bs[KC][NT];
  const int tid = threadIdx.x;
  const int m0 = blockIdx.x * MT;
  const int tm = tid >> 4, tn = tid & 15;

  float acc[4][CPT];
#pragma unroll
  for (int i = 0; i < 4; ++i)
#pragma unroll
    for (int j = 0; j < CPT; ++j) acc[i][j] = 0.f;

  const int kk4 = tid & 15;   // float4 index along K-chunk
  const int mr = tid >> 4;    // 0..15

  for (int kc = 0; kc < K; kc += KC) {
    // A tile: 64 rows x 64 k, transposed into LDS. 4 passes of 16 rows.
#pragma unroll
    for (int p = 0; p < 4; ++p) {
      int mm = p * 16 + mr;
      int m = m0 + mm;
      float4 v = make_float4(0.f, 0.f, 0.f, 0.f);
      if (m < M) v = *(const float4*)&A[(size_t)m * K + kc + kk4 * 4];
      As[kk4 * 4 + 0][mm] = v.x;
      As[kk4 * 4 + 1][mm] = v.y;
      As[kk4 * 4 + 2][mm] = v.z;
      As[kk4 * 4 + 3][mm] = v.w;
    }
    // B tile: [kk][n] straight copy (float4)
    const float4* BT4 = (const float4*)BT;
#pragma unroll
    for (int p = 0; p < (KC * NT / 4) / 256; ++p) {
      int idx = p * 256 + tid;
      int k2 = idx / (NT / 4), n4 = idx % (NT / 4);
      *(float4*)&Bs[k2][n4 * 4] = BT4[(size_t)(kc + k2) * (NT / 4) + n4];
    }
    __syncthreads();
#pragma unroll 8
    for (int k = 0; k < KC; ++k) {
      float4 a = *(const float4*)&As[k][tm * 4];
      float av[4] = {a.x, a.y, a.z, a.w};
      float bv[CPT];
#pragma unroll
      for (int j4 = 0; j4 < CPT; j4 += 4) {
        float4 b = *(const float4*)&Bs[k][tn * CPT + j4];
        bv[j4 + 0] = b.x; bv[j4 + 1] = b.y; bv[j4 + 2] = b.z; bv[j4 + 3] = b.w;
      }
#pragma unroll
      for (int i = 0; i < 4; ++i)
#pragma unroll
        for (int j = 0; j < CPT; ++j) acc[i][j] += av[i] * bv[j];
    }
    __syncthreads();
  }
  // epilogue
#pragma unroll
  for (int i = 0; i < 4; ++i) {
    int m = m0 + tm * 4 + i;
    if (m < M) {
      float vals[CPT];
#pragma unroll
      for (int j = 0; j < CPT; ++j) {
        float z = acc[i][j];
        if (BIAS) z += bias[tn * CPT + j];
        if (SWISH) z = swishf(z);
        vals[j] = z;
      }
#pragma unroll
      for (int j4 = 0; j4 < CPT; j4 += 4)
        *(float4*)&C[(size_t)m * NT + tn * CPT + j4] =
            make_float4(vals[j4], vals[j4 + 1], vals[j4 + 2], vals[j4 + 3]);
    }
  }
}

// ---------------- fused edge block: rbf_h, e-GEMM(K=384), t, scatter-add ----------------
__global__ __launch_bounds__(256) void k_edge_fused(
    const float* __restrict__ h,     // [N,128]
    const float* __restrict__ WlT,   // [384][128]
    const float* __restrict__ bl,    // [128]
    const float* __restrict__ rbf,   // [E][6]
    const float* __restrict__ WrT,   // [6][128]
    const float* __restrict__ br,    // [128]
    const float* __restrict__ WrbfT, // [6][128]
    const int* __restrict__ esrc, const int* __restrict__ edst,
    float* __restrict__ node,        // [N,128] accumulated atomically
    int E) {
  __shared__ alignas(16) float As[64][68];
  __shared__ alignas(16) float Bs[64][128];
  __shared__ float rbfS[64][7];   // padded (stride 7 -> 2-way max, free)
  __shared__ int dstS[64], srcS[64];
  __shared__ float blS[128], brS[128];

  const int tid = threadIdx.x;
  const int e0 = blockIdx.x * 64;
  if (tid < 64) {
    int e = e0 + tid;
    dstS[tid] = (e < E) ? edst[e] : 0;
    srcS[tid] = (e < E) ? esrc[e] : 0;
  } else {
    int c = tid - 64;
    if (c < 128) { blS[c] = bl[c]; }
  }
  if (tid >= 192) { int c = tid - 192; brS[c] = br[c]; brS[c + 64] = br[c + 64]; }
  for (int idx = tid; idx < 64 * NR; idx += 256) {
    int m = idx / NR, r = idx % NR;
    int e = e0 + m;
    rbfS[m][r] = (e < E) ? rbf[(size_t)e * NR + r] : 0.f;
  }
  __syncthreads();

  const int tm = tid >> 4, tn = tid & 15;
  float acc[4][8];
#pragma unroll
  for (int i = 0; i < 4; ++i)
#pragma unroll
    for (int j = 0; j < 8; ++j) acc[i][j] = 0.f;

  const int kk4 = tid & 15;
  const int mr = tid >> 4;

  for (int chunk = 0; chunk < 6; ++chunk) {
    if (chunk < 4) {
      // gather h rows (dst for chunks 0-1, src for 2-3), K-halves of 64
      const int* idxS = (chunk < 2) ? dstS : srcS;
      const int kb = (chunk & 1) * 64;
#pragma unroll
      for (int p = 0; p < 4; ++p) {
        int mm = p * 16 + mr;
        int row = idxS[mm];
        float4 v = *(const float4*)&h[(size_t)row * H + kb + kk4 * 4];
        As[kk4 * 4 + 0][mm] = v.x;
        As[kk4 * 4 + 1][mm] = v.y;
        As[kk4 * 4 + 2][mm] = v.z;
        As[kk4 * 4 + 3][mm] = v.w;
      }
    } else {
      // rbf_h on the fly: swish(rbf @ Wr^T + br), cols [cb, cb+64)
      const int cb = (chunk - 4) * 64;
      const int m = tid & 63;
      const int cg = tid >> 6; // 0..3
      float rb[NR];
#pragma unroll
      for (int r = 0; r < NR; ++r) rb[r] = rbfS[m][r];
#pragma unroll
      for (int q = 0; q < 16; ++q) {
        int co = cg * 16 + q;        // 0..63 within chunk
        int c = cb + co;             // 0..127
        float z = brS[c];
#pragma unroll
        for (int r = 0; r < NR; ++r) z += rb[r] * WrT[r * H + c];
        As[co][m] = swishf(z);
      }
    }
    // B tile from WlT rows [chunk*64, chunk*64+64)
    {
      const float4* B4 = (const float4*)WlT;
#pragma unroll
      for (int p = 0; p < 8; ++p) {
        int idx = p * 256 + tid;
        int k2 = idx >> 5, n4 = idx & 31;
        *(float4*)&Bs[k2][n4 * 4] = B4[(size_t)(chunk * 64 + k2) * 32 + n4];
      }
    }
    __syncthreads();
#pragma unroll 8
    for (int k = 0; k < 64; ++k) {
      float4 a = *(const float4*)&As[k][tm * 4];
      float av[4] = {a.x, a.y, a.z, a.w};
      float4 b0 = *(const float4*)&Bs[k][tn * 8];
      float4 b1 = *(const float4*)&Bs[k][tn * 8 + 4];
      float bv[8] = {b0.x, b0.y, b0.z, b0.w, b1.x, b1.y, b1.z, b1.w};
#pragma unroll
      for (int i = 0; i < 4; ++i)
#pragma unroll
        for (int j = 0; j < 8; ++j) acc[i][j] += av[i] * bv[j];
    }
    __syncthreads();
  }

  // epilogue: e = swish(z + bl); t = e * (rbf @ Wrbf^T); node[dst] += t
#pragma unroll
  for (int i = 0; i < 4; ++i) {
    int mm = tm * 4 + i;
    int e = e0 + mm;
    if (e < E) {
      int d = dstS[mm];
      float rb[NR];
#pragma unroll
      for (int r = 0; r < NR; ++r) rb[r] = rbfS[mm][r];
#pragma unroll
      for (int j = 0; j < 8; ++j) {
        int c = tn * 8 + j;
        float z = acc[i][j] + blS[c];
        float ev = swishf(z);
        float w = 0.f;
#pragma unroll
        for (int r = 0; r < NR; ++r) w += rb[r] * WrbfT[r * H + c];
        atomicAdd(&node[(size_t)d * H + c], ev * w);
      }
    }
  }
}

extern "C" void kernel_launch(void* const* d_in, const int* in_sizes, int n_in,
                              void* d_out, int out_size, void* d_ws, size_t ws_size,
                              hipStream_t stream) {
  const float* x    = (const float*)d_in[0];
  const float* pos  = (const float*)d_in[1];
  const float* freq = (const float*)d_in[2];
  const float* Wx   = (const float*)d_in[3];
  const float* Wr   = (const float*)d_in[4];
  const float* br   = (const float*)d_in[5];
  const float* Wl   = (const float*)d_in[6];
  const float* bl   = (const float*)d_in[7];
  const float* Wrbf = (const float*)d_in[8];
  const float* Wls  = (const float*)d_in[9];
  const float* bls  = (const float*)d_in[10];
  const float* Wout = (const float*)d_in[11];
  const int* esrc = (const int*)d_in[12];
  const int* edst = (const int*)d_in[13];
  const int* ii   = (const int*)d_in[14];
  const int* jjv  = (const int*)d_in[15];
  const int* kkv  = (const int*)d_in[16];

  const int N = in_sizes[0] / H;
  const int E = in_sizes[12];
  const int T = in_sizes[14];

  float* out   = (float*)d_out;
  float* P     = out;                       // [N,64]
  float* angle = out + (size_t)N * NOUT;    // [T]

  float* ws = (float*)d_ws;
  float* WxT   = ws; ws += H * H;       // [128][128]
  float* WlT   = ws; ws += 3 * H * H;   // [384][128]
  float* WlsT  = ws; ws += 3 * H * H;   // 3 x [128][128]
  float* WoutT = ws; ws += H * NOUT;    // [128][64]
  float* WrT   = ws; ws += NR * H;      // [6][128]
  float* WrbfT = ws; ws += NR * H;      // [6][128]
  float* rbf   = ws; ws += (size_t)E * NR;
  float* hbuf  = ws; ws += (size_t)N * H;
  float* nodeA = ws; ws += (size_t)N * H;
  float* nodeB = ws; ws += (size_t)N * H;

  // zero the segment-sum accumulator (ws is poisoned before every call)
  {
    int n4 = (N * H) / 4;
    k_zero4<<<(n4 + 255) / 256, 256, 0, stream>>>((float4*)nodeA, n4);
  }

  // weight transposes (tiny)
  k_transpose<<<(H * H + 255) / 256, 256, 0, stream>>>(Wx, WxT, H, H);
  k_transpose<<<(3 * H * H + 255) / 256, 256, 0, stream>>>(Wl, WlT, H, 3 * H);
  for (int k = 0; k < 3; ++k)
    k_transpose<<<(H * H + 255) / 256, 256, 0, stream>>>(Wls + k * H * H, WlsT + k * H * H, H, H);
  k_transpose<<<(NOUT * H + 255) / 256, 256, 0, stream>>>(Wout, WoutT, NOUT, H);
  k_transpose<<<(H * NR + 255) / 256, 256, 0, stream>>>(Wr, WrT, H, NR);
  k_transpose<<<(H * NR + 255) / 256, 256, 0, stream>>>(Wrbf, WrbfT, H, NR);

  // per-edge rbf and per-triplet angle
  k_rbf<<<(E + 255) / 256, 256, 0, stream>>>(pos, esrc, edst, freq, rbf, E);
  if (T > 0)
    k_angle<<<(T + 255) / 256, 256, 0, stream>>>(pos, ii, jjv, kkv, angle, T);

  // h = x @ Wx^T
  k_gemm_nt<128, false, false><<<(N + 63) / 64, 256, 0, stream>>>(x, WxT, nullptr, hbuf, N);

  // fused edge block -> segment sum into nodeA
  k_edge_fused<<<(E + 63) / 64, 256, 0, stream>>>(hbuf, WlT, bl, rbf, WrT, br, WrbfT,
                                                  esrc, edst, nodeA, E);

  // 3 swish layers + output projection
  k_gemm_nt<128, true, true><<<(N + 63) / 64, 256, 0, stream>>>(nodeA, WlsT, bls, nodeB, N);
  k_gemm_nt<128, true, true><<<(N + 63) / 64, 256, 0, stream>>>(nodeB, WlsT + H * H, bls + H, nodeA, N);
  k_gemm_nt<128, true, true><<<(N + 63) / 64, 256, 0, stream>>>(nodeA, WlsT + 2 * H * H, bls + 2 * H, nodeB, N);
  k_gemm_nt<64, false, false><<<(N + 63) / 64, 256, 0, stream>>>(nodeB, WoutT, nullptr, P, N);
}

// Round 3
// 669.959 us; speedup vs baseline: 2.7158x; 2.7158x over previous
//
#include <hip/hip_runtime.h>
#include <hip/hip_bf16.h>
#include <math.h>

#define H   128
#define NR  6
#define NOUT 64

typedef __attribute__((ext_vector_type(8))) short short8;
typedef __attribute__((ext_vector_type(4))) float floatx4;

__device__ __forceinline__ float swishf(float z) {
  float t = __expf(-z);
  return z / (1.0f + t);
}

__device__ __forceinline__ ushort f2bf(float x) {
  __hip_bfloat16 b = __float2bfloat16(x);
  return *reinterpret_cast<ushort*>(&b);
}

// ---------------- zero fill (float4) ----------------
__global__ void k_zero4(float4* __restrict__ p, int n4) {
  int i = blockIdx.x * blockDim.x + threadIdx.x;
  if (i < n4) p[i] = make_float4(0.f, 0.f, 0.f, 0.f);
}

// ---------------- tiny transpose: out[c][r] = in[r][c] ----------------
__global__ void k_transpose(const float* __restrict__ in, float* __restrict__ out,
                            int rows, int cols) {
  int idx = blockIdx.x * blockDim.x + threadIdx.x;
  if (idx >= rows * cols) return;
  int r = idx / cols, c = idx % cols;
  out[c * rows + r] = in[idx];
}

// ---------------- fp32 -> bf16 convert ----------------
__global__ void k_f32_to_bf16(const float* __restrict__ in, ushort* __restrict__ out, int n) {
  int i = blockIdx.x * blockDim.x + threadIdx.x;
  if (i < n) out[i] = f2bf(in[i]);
}

// ---------------- per-edge Bessel-RBF with envelope ----------------
__global__ void k_rbf(const float* __restrict__ pos, const int* __restrict__ src,
                      const int* __restrict__ dst, const float* __restrict__ freq,
                      float* __restrict__ rbf, int E) {
  int e = blockIdx.x * blockDim.x + threadIdx.x;
  if (e >= E) return;
  int s = src[e], d = dst[e];
  float dx = pos[d * 3 + 0] - pos[s * 3 + 0];
  float dy = pos[d * 3 + 1] - pos[s * 3 + 1];
  float dz = pos[d * 3 + 2] - pos[s * 3 + 2];
  float dist = sqrtf(dx * dx + dy * dy + dz * dz);
  float dn = dist * 0.2f;
  float inv = 1.0f / dn;
  float dn2 = dn * dn;
  float dp = dn2 * dn2 * dn;                    // dn^5 (p=5)
  float env = inv - 21.0f * dp + 35.0f * dp * dn - 15.0f * dp * dn2;
  float fr[NR];
#pragma unroll
  for (int r = 0; r < NR; ++r) fr[r] = freq[r];
#pragma unroll
  for (int r = 0; r < NR; ++r)
    rbf[(size_t)e * NR + r] = env * sinf(fr[r] * dn);
}

// ---------------- triplet angles ----------------
__global__ void k_angle(const float* __restrict__ pos, const int* __restrict__ ii,
                        const int* __restrict__ jj, const int* __restrict__ kk,
                        float* __restrict__ out, int T) {
  int t = blockIdx.x * blockDim.x + threadIdx.x;
  if (t >= T) return;
  int i = ii[t], j = jj[t], k = kk[t];
  float pix = pos[i * 3], piy = pos[i * 3 + 1], piz = pos[i * 3 + 2];
  float vjx = pos[j * 3] - pix, vjy = pos[j * 3 + 1] - piy, vjz = pos[j * 3 + 2] - piz;
  float vkx = pos[k * 3] - pix, vky = pos[k * 3 + 1] - piy, vkz = pos[k * 3 + 2] - piz;
  float a = vjx * vkx + vjy * vky + vjz * vkz;
  float cx = vjy * vkz - vjz * vky;
  float cy = vjz * vkx - vjx * vkz;
  float cz = vjx * vky - vjy * vkx;
  float b = sqrtf(cx * cx + cy * cy + cz * cz);
  out[t] = atan2f(b, a);
}

// ---------------- generic NT fp32 GEMM: C = act(A[M,128] @ BT[128,NT] + bias) ----------------
template <int NT, bool SWISH, bool BIAS, bool OUT_BF16>
__global__ __launch_bounds__(256) void k_gemm_nt(
    const float* __restrict__ A,    // [M,128]
    const float* __restrict__ BT,   // [128][NT]  (pre-transposed weights)
    const float* __restrict__ bias, // [NT] or null
    void* __restrict__ C,           // [M,NT] fp32 or bf16
    int M) {
  constexpr int K = 128, MT = 64, KC = 64;
  constexpr int CPT = NT / 16; // cols per thread (8 or 4)
  __shared__ alignas(16) float As[KC][68];
  __shared__ alignas(16) float Bs[KC][NT];
  const int tid = threadIdx.x;
  const int m0 = blockIdx.x * MT;
  const int tm = tid >> 4, tn = tid & 15;

  float acc[4][CPT];
#pragma unroll
  for (int i = 0; i < 4; ++i)
#pragma unroll
    for (int j = 0; j < CPT; ++j) acc[i][j] = 0.f;

  const int kk4 = tid & 15;
  const int mr = tid >> 4;

  for (int kc = 0; kc < K; kc += KC) {
#pragma unroll
    for (int p = 0; p < 4; ++p) {
      int mm = p * 16 + mr;
      int m = m0 + mm;
      float4 v = make_float4(0.f, 0.f, 0.f, 0.f);
      if (m < M) v = *(const float4*)&A[(size_t)m * K + kc + kk4 * 4];
      As[kk4 * 4 + 0][mm] = v.x;
      As[kk4 * 4 + 1][mm] = v.y;
      As[kk4 * 4 + 2][mm] = v.z;
      As[kk4 * 4 + 3][mm] = v.w;
    }
    const float4* BT4 = (const float4*)BT;
#pragma unroll
    for (int p = 0; p < (KC * NT / 4) / 256; ++p) {
      int idx = p * 256 + tid;
      int k2 = idx / (NT / 4), n4 = idx % (NT / 4);
      *(float4*)&Bs[k2][n4 * 4] = BT4[(size_t)(kc + k2) * (NT / 4) + n4];
    }
    __syncthreads();
#pragma unroll 8
    for (int k = 0; k < KC; ++k) {
      float4 a = *(const float4*)&As[k][tm * 4];
      float av[4] = {a.x, a.y, a.z, a.w};
      float bv[CPT];
#pragma unroll
      for (int j4 = 0; j4 < CPT; j4 += 4) {
        float4 b = *(const float4*)&Bs[k][tn * CPT + j4];
        bv[j4 + 0] = b.x; bv[j4 + 1] = b.y; bv[j4 + 2] = b.z; bv[j4 + 3] = b.w;
      }
#pragma unroll
      for (int i = 0; i < 4; ++i)
#pragma unroll
        for (int j = 0; j < CPT; ++j) acc[i][j] += av[i] * bv[j];
    }
    __syncthreads();
  }
#pragma unroll
  for (int i = 0; i < 4; ++i) {
    int m = m0 + tm * 4 + i;
    if (m < M) {
      float vals[CPT];
#pragma unroll
      for (int j = 0; j < CPT; ++j) {
        float z = acc[i][j];
        if (BIAS) z += bias[tn * CPT + j];
        if (SWISH) z = swishf(z);
        vals[j] = z;
      }
      if (OUT_BF16) {
        ushort* Cb = (ushort*)C;
        short8 pk;
#pragma unroll
        for (int j = 0; j < CPT; ++j) pk[j] = (short)f2bf(vals[j]);
        *(short8*)&Cb[(size_t)m * NT + tn * CPT] = pk;  // CPT==8 -> 16B store
      } else {
        float* Cf = (float*)C;
#pragma unroll
        for (int j4 = 0; j4 < CPT; j4 += 4)
          *(float4*)&Cf[(size_t)m * NT + tn * CPT + j4] =
              make_float4(vals[j4], vals[j4 + 1], vals[j4 + 2], vals[j4 + 3]);
      }
    }
  }
}

// ---------------- MFMA fused edge block ----------------
// Tile: 128 edges x 128 cols, K=384 (h_dst|h_src|rbf_h) in 6 chunks of 64.
// 4 waves in 2x2; each wave: 64x64 = 4x4 tiles of 16x16, mfma_f32_16x16x32_bf16.
// LDS bf16 tiles use XOR swizzle (16B group g stored at g^(row&7)) -> conflict-free b128.
__global__ __launch_bounds__(256) void k_edge_mfma(
    const ushort* __restrict__ hbf,    // [N][128] bf16
    const ushort* __restrict__ Wlbf,   // [128][384] bf16 (n-major, original Wl layout)
    const float* __restrict__ bl,      // [128]
    const float* __restrict__ rbf,     // [E][6]
    const float* __restrict__ WrT,     // [6][128]
    const float* __restrict__ br,      // [128]
    const float* __restrict__ WrbfT,   // [6][128]
    const int* __restrict__ esrc, const int* __restrict__ edst,
    float* __restrict__ node,          // [N,128] accumulated atomically
    int E) {
  __shared__ ushort As[128 * 64];
  __shared__ ushort Bs[128 * 64];
  __shared__ float rbfS[128][8];
  __shared__ float wrS[NR][128];
  __shared__ float brS[128];
  __shared__ int dstS[128];
  __shared__ int srcS[128];

  const int tid = threadIdx.x;
  const int e0 = blockIdx.x * 128;

  if (tid < 128) {
    int e = min(e0 + tid, E - 1);
    dstS[tid] = edst[e];
    srcS[tid] = esrc[e];
    brS[tid] = br[tid];
  }
  // rbf rows (6 valid per row)
  for (int idx = tid; idx < 128 * NR; idx += 256) {
    int m = idx / NR, r = idx % NR;
    int e = e0 + m;
    rbfS[m][r] = (e < E) ? rbf[(size_t)e * NR + r] : 0.f;
  }
  for (int idx = tid; idx < NR * 128; idx += 256) {
    int r = idx >> 7, c = idx & 127;
    wrS[r][c] = WrT[r * H + c];
  }
  __syncthreads();

  const int w = tid >> 6;
  const int lane = tid & 63;
  const int l15 = lane & 15, quad = lane >> 4;
  const int wm = (w >> 1) * 64;   // edge-strip base
  const int wn = (w & 1) * 64;    // col-strip base

  const floatx4 vzero = {0.f, 0.f, 0.f, 0.f};
  floatx4 acc[4][4];
#pragma unroll
  for (int i = 0; i < 4; ++i)
#pragma unroll
    for (int j = 0; j < 4; ++j) acc[i][j] = vzero;

  for (int c = 0; c < 6; ++c) {
    // ---- stage A tile (128 edges x 64 k, bf16, swizzled) ----
    if (c < 4) {
      const int* idxS = (c < 2) ? dstS : srcS;
      const int off = (c & 1) * 64;
#pragma unroll
      for (int p = 0; p < 4; ++p) {
        int idx = p * 256 + tid;            // 0..1023
        int m = idx >> 3, g = idx & 7;
        int row = idxS[m];
        uint4 v = *(const uint4*)(hbf + (size_t)row * H + off + g * 8);
        *(uint4*)(As + (m * 8 + (g ^ (m & 7))) * 8) = v;
      }
    } else {
      const int off = (c & 1) * 64;
#pragma unroll
      for (int p = 0; p < 4; ++p) {
        int idx = p * 256 + tid;
        int m = idx >> 3, g = idx & 7;
        float rb[NR];
#pragma unroll
        for (int r = 0; r < NR; ++r) rb[r] = rbfS[m][r];
        short8 pk;
#pragma unroll
        for (int j = 0; j < 8; ++j) {
          int col = off + g * 8 + j;
          float z = brS[col];
#pragma unroll
          for (int r = 0; r < NR; ++r) z += rb[r] * wrS[r][col];
          pk[j] = (short)f2bf(swishf(z));
        }
        *(short8*)(As + (m * 8 + (g ^ (m & 7))) * 8) = pk;
      }
    }
    // ---- stage B tile (128 cols x 64 k from Wlbf rows, swizzled) ----
#pragma unroll
    for (int p = 0; p < 4; ++p) {
      int idx = p * 256 + tid;
      int n = idx >> 3, g = idx & 7;
      uint4 v = *(const uint4*)(Wlbf + (size_t)n * 384 + c * 64 + g * 8);
      *(uint4*)(Bs + (n * 8 + (g ^ (n & 7))) * 8) = v;
    }
    __syncthreads();
    // ---- MFMA: 2 K-steps of 32 ----
#pragma unroll
    for (int s = 0; s < 2; ++s) {
      const int gg = s * 4 + quad;
      short8 af[4], bfr[4];
#pragma unroll
      for (int i = 0; i < 4; ++i) {
        int m = wm + i * 16 + l15;
        af[i] = *(const short8*)(As + (m * 8 + (gg ^ (m & 7))) * 8);
      }
#pragma unroll
      for (int j = 0; j < 4; ++j) {
        int n = wn + j * 16 + l15;
        bfr[j] = *(const short8*)(Bs + (n * 8 + (gg ^ (n & 7))) * 8);
      }
#pragma unroll
      for (int i = 0; i < 4; ++i)
#pragma unroll
        for (int j = 0; j < 4; ++j)
          acc[i][j] = __builtin_amdgcn_mfma_f32_16x16x32_bf16(af[i], bfr[j], acc[i][j], 0, 0, 0);
    }
    __syncthreads();
  }

  // ---- epilogue: e = swish(z+bl); t = e * (rbf@WrbfT); node[dst] += t ----
  float wt[4][NR], blv[4];
#pragma unroll
  for (int j = 0; j < 4; ++j) {
    int n = wn + j * 16 + l15;
    blv[j] = bl[n];
#pragma unroll
    for (int r = 0; r < NR; ++r) wt[j][r] = WrbfT[r * H + n];
  }
#pragma unroll
  for (int i = 0; i < 4; ++i) {
#pragma unroll
    for (int r = 0; r < 4; ++r) {
      int m = wm + i * 16 + quad * 4 + r;
      int e = e0 + m;
      if (e < E) {
        float rb[NR];
#pragma unroll
        for (int q = 0; q < NR; ++q) rb[q] = rbfS[m][q];
        int drow = dstS[m];
#pragma unroll
        for (int j = 0; j < 4; ++j) {
          int n = wn + j * 16 + l15;
          float z = acc[i][j][r] + blv[j];
          float ev = swishf(z);
          float wv = 0.f;
#pragma unroll
          for (int q = 0; q < NR; ++q) wv += rb[q] * wt[j][q];
          atomicAdd(&node[(size_t)drow * H + n], ev * wv);
        }
      }
    }
  }
}

extern "C" void kernel_launch(void* const* d_in, const int* in_sizes, int n_in,
                              void* d_out, int out_size, void* d_ws, size_t ws_size,
                              hipStream_t stream) {
  const float* x    = (const float*)d_in[0];
  const float* pos  = (const float*)d_in[1];
  const float* freq = (const float*)d_in[2];
  const float* Wx   = (const float*)d_in[3];
  const float* Wr   = (const float*)d_in[4];
  const float* br   = (const float*)d_in[5];
  const float* Wl   = (const float*)d_in[6];
  const float* bl   = (const float*)d_in[7];
  const float* Wrbf = (const float*)d_in[8];
  const float* Wls  = (const float*)d_in[9];
  const float* bls  = (const float*)d_in[10];
  const float* Wout = (const float*)d_in[11];
  const int* esrc = (const int*)d_in[12];
  const int* edst = (const int*)d_in[13];
  const int* ii   = (const int*)d_in[14];
  const int* jjv  = (const int*)d_in[15];
  const int* kkv  = (const int*)d_in[16];

  const int N = in_sizes[0] / H;
  const int E = in_sizes[12];
  const int T = in_sizes[14];

  float* out   = (float*)d_out;
  float* P     = out;                       // [N,64]
  float* angle = out + (size_t)N * NOUT;    // [T]

  float* ws = (float*)d_ws;
  float* WxT   = ws; ws += H * H;         // 16384
  float* WlsT  = ws; ws += 3 * H * H;     // 49152
  float* WoutT = ws; ws += H * NOUT;      // 8192
  float* WrT   = ws; ws += NR * H;        // 768
  float* WrbfT = ws; ws += NR * H;        // 768
  float* rbf   = ws; ws += (size_t)E * NR;
  float* nodeA = ws; ws += (size_t)N * H;
  float* nodeB = ws; ws += (size_t)N * H;
  ushort* hbf  = (ushort*)ws; ws += ((size_t)N * H + 1) / 2;
  ushort* Wlbf = (ushort*)ws; ws += (3 * H * H + 1) / 2;

  // zero the segment-sum accumulator
  {
    int n4 = (N * H) / 4;
    k_zero4<<<(n4 + 255) / 256, 256, 0, stream>>>((float4*)nodeA, n4);
  }

  // weight transposes / converts (tiny)
  k_transpose<<<(H * H + 255) / 256, 256, 0, stream>>>(Wx, WxT, H, H);
  for (int k = 0; k < 3; ++k)
    k_transpose<<<(H * H + 255) / 256, 256, 0, stream>>>(Wls + k * H * H, WlsT + k * H * H, H, H);
  k_transpose<<<(NOUT * H + 255) / 256, 256, 0, stream>>>(Wout, WoutT, NOUT, H);
  k_transpose<<<(H * NR + 255) / 256, 256, 0, stream>>>(Wr, WrT, H, NR);
  k_transpose<<<(H * NR + 255) / 256, 256, 0, stream>>>(Wrbf, WrbfT, H, NR);
  k_f32_to_bf16<<<(3 * H * H + 255) / 256, 256, 0, stream>>>(Wl, Wlbf, 3 * H * H);

  // per-edge rbf and per-triplet angle
  k_rbf<<<(E + 255) / 256, 256, 0, stream>>>(pos, esrc, edst, freq, rbf, E);
  if (T > 0)
    k_angle<<<(T + 255) / 256, 256, 0, stream>>>(pos, ii, jjv, kkv, angle, T);

  // h = x @ Wx^T  -> bf16 directly
  k_gemm_nt<128, false, false, true><<<(N + 63) / 64, 256, 0, stream>>>(x, WxT, nullptr, hbf, N);

  // fused MFMA edge block -> segment sum into nodeA
  k_edge_mfma<<<(E + 127) / 128, 256, 0, stream>>>(hbf, Wlbf, bl, rbf, WrT, br, WrbfT,
                                                   esrc, edst, nodeA, E);

  // 3 swish layers + output projection (fp32)
  k_gemm_nt<128, true, true, false><<<(N + 63) / 64, 256, 0, stream>>>(nodeA, WlsT, bls, nodeB, N);
  k_gemm_nt<128, true, true, false><<<(N + 63) / 64, 256, 0, stream>>>(nodeB, WlsT + H * H, bls + H, nodeA, N);
  k_gemm_nt<128, true, true, false><<<(N + 63) / 64, 256, 0, stream>>>(nodeA, WlsT + 2 * H * H, bls + 2 * H, nodeB, N);
  k_gemm_nt<64, false, false, false><<<(N + 63) / 64, 256, 0, stream>>>(nodeB, WoutT, nullptr, P, N);
}

// Round 4
// 571.158 us; speedup vs baseline: 3.1856x; 1.1730x over previous
//
#include <hip/hip_runtime.h>
#include <hip/hip_bf16.h>
#include <math.h>

#define H   128
#define NR  6
#define NOUT 64

typedef __attribute__((ext_vector_type(8))) short short8;
typedef __attribute__((ext_vector_type(4))) float floatx4;

__device__ __forceinline__ float swishf(float z) {
  float t = __expf(-z);
  return z / (1.0f + t);
}

__device__ __forceinline__ ushort f2bf(float x) {
  __hip_bfloat16 b = __float2bfloat16(x);
  return *reinterpret_cast<ushort*>(&b);
}

__device__ __forceinline__ float bf2f(ushort u) {
  unsigned int v = ((unsigned int)u) << 16;
  return __uint_as_float(v);
}

// async 16B global->LDS (wave-uniform LDS base + lane*16)
__device__ __forceinline__ void async_copy16(const void* g, void* l) {
  __builtin_amdgcn_global_load_lds(
      (const __attribute__((address_space(1))) unsigned int*)g,
      (__attribute__((address_space(3))) unsigned int*)l, 16, 0, 0);
}

// ---------------- zero fill (float4) ----------------
__global__ void k_zero4(float4* __restrict__ p, int n4) {
  int i = blockIdx.x * blockDim.x + threadIdx.x;
  if (i < n4) p[i] = make_float4(0.f, 0.f, 0.f, 0.f);
}

// ---------------- tiny transpose: out[c][r] = in[r][c] ----------------
__global__ void k_transpose(const float* __restrict__ in, float* __restrict__ out,
                            int rows, int cols) {
  int idx = blockIdx.x * blockDim.x + threadIdx.x;
  if (idx >= rows * cols) return;
  int r = idx / cols, c = idx % cols;
  out[c * rows + r] = in[idx];
}

// ---------------- fp32 -> bf16 convert ----------------
__global__ void k_f32_to_bf16(const float* __restrict__ in, ushort* __restrict__ out, int n) {
  int i = blockIdx.x * blockDim.x + threadIdx.x;
  if (i < n) out[i] = f2bf(in[i]);
}

// ---------------- per-edge features: rbf[E][6] fp32 + rbf_h[E][128] bf16 ----------------
// 256 threads / 64 edges per block; thread t -> edge (t>>2), col-group (t&3)*32.
__global__ __launch_bounds__(256) void k_edge_feat(
    const float* __restrict__ pos, const int* __restrict__ esrc,
    const int* __restrict__ edst, const float* __restrict__ freq,
    const float* __restrict__ Wr,   // [128][6] original layout
    const float* __restrict__ br,   // [128]
    float* __restrict__ rbfG,       // [E][6]
    ushort* __restrict__ rbfh,      // [E][128] bf16
    int E) {
  __shared__ float wrS[128][6];
  __shared__ float brS[128];
  const int tid = threadIdx.x;
  for (int idx = tid; idx < 128 * 6; idx += 256) wrS[idx / 6][idx % 6] = Wr[idx];
  if (tid < 128) brS[tid] = br[tid];
  __syncthreads();

  const int e = blockIdx.x * 64 + (tid >> 2);
  if (e >= E) return;
  const int cg = (tid & 3) * 32;

  const int s = esrc[e], d = edst[e];
  float dx = pos[d * 3 + 0] - pos[s * 3 + 0];
  float dy = pos[d * 3 + 1] - pos[s * 3 + 1];
  float dz = pos[d * 3 + 2] - pos[s * 3 + 2];
  float dist = sqrtf(dx * dx + dy * dy + dz * dz);
  float dn = dist * 0.2f;
  float inv = 1.0f / dn;
  float dn2 = dn * dn;
  float dp = dn2 * dn2 * dn;  // dn^5
  float env = inv - 21.0f * dp + 35.0f * dp * dn - 15.0f * dp * dn2;
  float rb[NR];
#pragma unroll
  for (int r = 0; r < NR; ++r) rb[r] = env * sinf(freq[r] * dn);

  if ((tid & 3) == 0) {
#pragma unroll
    for (int r = 0; r < NR; ++r) rbfG[(size_t)e * NR + r] = rb[r];
  }

#pragma unroll
  for (int q = 0; q < 4; ++q) {
    short8 pk;
#pragma unroll
    for (int j = 0; j < 8; ++j) {
      int c = cg + q * 8 + j;
      float z = brS[c];
#pragma unroll
      for (int r = 0; r < NR; ++r) z += rb[r] * wrS[c][r];
      pk[j] = (short)f2bf(swishf(z));
    }
    *(short8*)(rbfh + (size_t)e * H + cg + q * 8) = pk;
  }
}

// ---------------- triplet angles ----------------
__global__ void k_angle(const float* __restrict__ pos, const int* __restrict__ ii,
                        const int* __restrict__ jj, const int* __restrict__ kk,
                        float* __restrict__ out, int T) {
  int t = blockIdx.x * blockDim.x + threadIdx.x;
  if (t >= T) return;
  int i = ii[t], j = jj[t], k = kk[t];
  float pix = pos[i * 3], piy = pos[i * 3 + 1], piz = pos[i * 3 + 2];
  float vjx = pos[j * 3] - pix, vjy = pos[j * 3 + 1] - piy, vjz = pos[j * 3 + 2] - piz;
  float vkx = pos[k * 3] - pix, vky = pos[k * 3 + 1] - piy, vkz = pos[k * 3 + 2] - piz;
  float a = vjx * vkx + vjy * vky + vjz * vkz;
  float cx = vjy * vkz - vjz * vky;
  float cy = vjz * vkx - vjx * vkz;
  float cz = vjx * vky - vjy * vkx;
  float b = sqrtf(cx * cx + cy * cy + cz * cz);
  out[t] = atan2f(b, a);
}

// ---------------- generic NT fp32 GEMM: C = act(A[M,128] @ BT[128,NT] + bias) ----------------
template <int NT, bool SWISH, bool BIAS, bool OUT_BF16>
__global__ __launch_bounds__(256) void k_gemm_nt(
    const float* __restrict__ A,
    const float* __restrict__ BT,
    const float* __restrict__ bias,
    void* __restrict__ C,
    int M) {
  constexpr int K = 128, MT = 64, KC = 64;
  constexpr int CPT = NT / 16;
  __shared__ alignas(16) float As[KC][68];
  __shared__ alignas(16) float Bs[KC][NT];
  const int tid = threadIdx.x;
  const int m0 = blockIdx.x * MT;
  const int tm = tid >> 4, tn = tid & 15;

  float acc[4][CPT];
#pragma unroll
  for (int i = 0; i < 4; ++i)
#pragma unroll
    for (int j = 0; j < CPT; ++j) acc[i][j] = 0.f;

  const int kk4 = tid & 15;
  const int mr = tid >> 4;

  for (int kc = 0; kc < K; kc += KC) {
#pragma unroll
    for (int p = 0; p < 4; ++p) {
      int mm = p * 16 + mr;
      int m = m0 + mm;
      float4 v = make_float4(0.f, 0.f, 0.f, 0.f);
      if (m < M) v = *(const float4*)&A[(size_t)m * K + kc + kk4 * 4];
      As[kk4 * 4 + 0][mm] = v.x;
      As[kk4 * 4 + 1][mm] = v.y;
      As[kk4 * 4 + 2][mm] = v.z;
      As[kk4 * 4 + 3][mm] = v.w;
    }
    const float4* BT4 = (const float4*)BT;
#pragma unroll
    for (int p = 0; p < (KC * NT / 4) / 256; ++p) {
      int idx = p * 256 + tid;
      int k2 = idx / (NT / 4), n4 = idx % (NT / 4);
      *(float4*)&Bs[k2][n4 * 4] = BT4[(size_t)(kc + k2) * (NT / 4) + n4];
    }
    __syncthreads();
#pragma unroll 8
    for (int k = 0; k < KC; ++k) {
      float4 a = *(const float4*)&As[k][tm * 4];
      float av[4] = {a.x, a.y, a.z, a.w};
      float bv[CPT];
#pragma unroll
      for (int j4 = 0; j4 < CPT; j4 += 4) {
        float4 b = *(const float4*)&Bs[k][tn * CPT + j4];
        bv[j4 + 0] = b.x; bv[j4 + 1] = b.y; bv[j4 + 2] = b.z; bv[j4 + 3] = b.w;
      }
#pragma unroll
      for (int i = 0; i < 4; ++i)
#pragma unroll
        for (int j = 0; j < CPT; ++j) acc[i][j] += av[i] * bv[j];
    }
    __syncthreads();
  }
#pragma unroll
  for (int i = 0; i < 4; ++i) {
    int m = m0 + tm * 4 + i;
    if (m < M) {
      float vals[CPT];
#pragma unroll
      for (int j = 0; j < CPT; ++j) {
        float z = acc[i][j];
        if (BIAS) z += bias[tn * CPT + j];
        if (SWISH) z = swishf(z);
        vals[j] = z;
      }
      if (OUT_BF16) {
        ushort* Cb = (ushort*)C;
        short8 pk;
#pragma unroll
        for (int j = 0; j < CPT; ++j) pk[j] = (short)f2bf(vals[j]);
        *(short8*)&Cb[(size_t)m * NT + tn * CPT] = pk;
      } else {
        float* Cf = (float*)C;
#pragma unroll
        for (int j4 = 0; j4 < CPT; j4 += 4)
          *(float4*)&Cf[(size_t)m * NT + tn * CPT + j4] =
              make_float4(vals[j4], vals[j4 + 1], vals[j4 + 2], vals[j4 + 3]);
      }
    }
  }
}

// ---------------- MFMA fused edge block (async staging) ----------------
// Tile: 128 edges x 128 cols, K=384 = [h_dst | h_src | rbf_h] in 6 chunks of 64.
// A/B tiles staged via global_load_lds (16B/lane); XOR swizzle preserved by
// inverse-swizzling the GLOBAL address (LDS dest must be base + lane*16).
__global__ __launch_bounds__(256, 4) void k_edge_mfma(
    const ushort* __restrict__ hbf,    // [N][128] bf16
    const ushort* __restrict__ rbfh,   // [E][128] bf16
    const ushort* __restrict__ Wlbf,   // [128][384] bf16 (original Wl layout)
    const float* __restrict__ bl,      // [128]
    const float* __restrict__ rbfG,    // [E][6]
    const float* __restrict__ Wrbf,    // [128][6] original layout
    const int* __restrict__ esrc, const int* __restrict__ edst,
    float* __restrict__ node,          // [N,128] accumulated atomically
    int E) {
  __shared__ ushort As[128 * 64];   // 16 KB
  __shared__ ushort Bs[128 * 64];   // 16 KB
  __shared__ float rbfS[128][6];    // 3 KB
  __shared__ int dstS[128];
  __shared__ int srcS[128];
  __shared__ float blS[128];

  const int tid = threadIdx.x;
  const int e0 = blockIdx.x * 128;

  if (tid < 128) {
    int e = min(e0 + tid, E - 1);
    dstS[tid] = edst[e];
    srcS[tid] = esrc[e];
    blS[tid] = bl[tid];
  }
  for (int idx = tid; idx < 128 * NR; idx += 256) {
    int gidx = e0 * NR + idx;
    ((float*)rbfS)[idx] = (gidx < E * NR) ? rbfG[gidx] : 0.f;
  }
  __syncthreads();

  const int w = tid >> 6;
  const int lane = tid & 63;
  const int l15 = lane & 15, quad = lane >> 4;
  const int wm = (w >> 1) * 64;
  const int wn = (w & 1) * 64;
  const int wslot = w * 256;        // this wave's 16B-slot base in As/Bs

  const floatx4 vzero = {0.f, 0.f, 0.f, 0.f};
  floatx4 acc[4][4];
#pragma unroll
  for (int i = 0; i < 4; ++i)
#pragma unroll
    for (int j = 0; j < 4; ++j) acc[i][j] = vzero;

  const int Em1 = E - 1;

  for (int c = 0; c < 6; ++c) {
    // ---- stage A tile: 1024 16B slots, each wave covers 256 (4 issues of 64) ----
    {
      const int* rowS = (c < 2) ? dstS : ((c < 4) ? srcS : nullptr);
      const ushort* base = (c < 4) ? hbf : rbfh;
      const int off = (c & 1) * 64;
#pragma unroll
      for (int i = 0; i < 4; ++i) {
        int u = wslot + i * 64 + lane;
        int nrow = u >> 3, gp = u & 7;
        int g = gp ^ (nrow & 7);            // inverse swizzle on global side
        int row = rowS ? rowS[nrow] : min(e0 + nrow, Em1);
        const ushort* gsrc = base + (size_t)row * H + off + g * 8;
        int lb = __builtin_amdgcn_readfirstlane(wslot + i * 64);
        async_copy16((const void*)gsrc, (void*)(As + lb * 8));
      }
    }
    // ---- stage B tile from Wlbf rows (sequential), k-slice c*64 ----
    {
#pragma unroll
      for (int i = 0; i < 4; ++i) {
        int u = wslot + i * 64 + lane;
        int nrow = u >> 3, gp = u & 7;
        int g = gp ^ (nrow & 7);
        const ushort* gsrc = Wlbf + (size_t)nrow * 384 + c * 64 + g * 8;
        int lb = __builtin_amdgcn_readfirstlane(wslot + i * 64);
        async_copy16((const void*)gsrc, (void*)(Bs + lb * 8));
      }
    }
    __syncthreads();   // compiler drains vmcnt before barrier -> staging complete
    // ---- MFMA: 2 K-steps of 32 ----
#pragma unroll
    for (int s = 0; s < 2; ++s) {
      const int gg = s * 4 + quad;
      short8 af[4], bfr[4];
#pragma unroll
      for (int i = 0; i < 4; ++i) {
        int m = wm + i * 16 + l15;
        af[i] = *(const short8*)(As + (m * 8 + (gg ^ (m & 7))) * 8);
      }
#pragma unroll
      for (int j = 0; j < 4; ++j) {
        int n = wn + j * 16 + l15;
        bfr[j] = *(const short8*)(Bs + (n * 8 + (gg ^ (n & 7))) * 8);
      }
#pragma unroll
      for (int i = 0; i < 4; ++i)
#pragma unroll
        for (int j = 0; j < 4; ++j)
          acc[i][j] = __builtin_amdgcn_mfma_f32_16x16x32_bf16(af[i], bfr[j], acc[i][j], 0, 0, 0);
    }
    __syncthreads();
  }

  // ---- epilogue: e = swish(z+bl); t = e * (rbf . Wrbf[n,:]); node[dst] += t ----
  float wt[4][NR], blv[4];
#pragma unroll
  for (int j = 0; j < 4; ++j) {
    int n = wn + j * 16 + l15;
    blv[j] = blS[n];
#pragma unroll
    for (int r = 0; r < NR; ++r) wt[j][r] = Wrbf[n * NR + r];
  }
#pragma unroll
  for (int i = 0; i < 4; ++i) {
#pragma unroll
    for (int r = 0; r < 4; ++r) {
      int m = wm + i * 16 + quad * 4 + r;
      int e = e0 + m;
      if (e < E) {
        float rb[NR];
#pragma unroll
        for (int q = 0; q < NR; ++q) rb[q] = rbfS[m][q];
        int drow = dstS[m];
#pragma unroll
        for (int j = 0; j < 4; ++j) {
          int n = wn + j * 16 + l15;
          float z = acc[i][j][r] + blv[j];
          float ev = swishf(z);
          float wv = 0.f;
#pragma unroll
          for (int q = 0; q < NR; ++q) wv += rb[q] * wt[j][q];
          atomicAdd(&node[(size_t)drow * H + n], ev * wv);
        }
      }
    }
  }
}

extern "C" void kernel_launch(void* const* d_in, const int* in_sizes, int n_in,
                              void* d_out, int out_size, void* d_ws, size_t ws_size,
                              hipStream_t stream) {
  const float* x    = (const float*)d_in[0];
  const float* pos  = (const float*)d_in[1];
  const float* freq = (const float*)d_in[2];
  const float* Wx   = (const float*)d_in[3];
  const float* Wr   = (const float*)d_in[4];
  const float* br   = (const float*)d_in[5];
  const float* Wl   = (const float*)d_in[6];
  const float* bl   = (const float*)d_in[7];
  const float* Wrbf = (const float*)d_in[8];
  const float* Wls  = (const float*)d_in[9];
  const float* bls  = (const float*)d_in[10];
  const float* Wout = (const float*)d_in[11];
  const int* esrc = (const int*)d_in[12];
  const int* edst = (const int*)d_in[13];
  const int* ii   = (const int*)d_in[14];
  const int* jjv  = (const int*)d_in[15];
  const int* kkv  = (const int*)d_in[16];

  const int N = in_sizes[0] / H;
  const int E = in_sizes[12];
  const int T = in_sizes[14];

  float* out   = (float*)d_out;
  float* P     = out;                       // [N,64]
  float* angle = out + (size_t)N * NOUT;    // [T]

  float* ws = (float*)d_ws;
  float* WxT   = ws; ws += H * H;
  float* WlsT  = ws; ws += 3 * H * H;
  float* WoutT = ws; ws += H * NOUT;
  float* rbfG  = ws; ws += (size_t)E * NR;
  float* nodeA = ws; ws += (size_t)N * H;
  float* nodeB = ws; ws += (size_t)N * H;
  ushort* hbf  = (ushort*)ws; ws += ((size_t)N * H + 1) / 2;
  ushort* Wlbf = (ushort*)ws; ws += (3 * H * H + 1) / 2;
  ushort* rbfh = (ushort*)ws; ws += ((size_t)E * H + 1) / 2;

  // zero the segment-sum accumulator
  {
    int n4 = (N * H) / 4;
    k_zero4<<<(n4 + 255) / 256, 256, 0, stream>>>((float4*)nodeA, n4);
  }

  // weight transposes / converts (tiny)
  k_transpose<<<(H * H + 255) / 256, 256, 0, stream>>>(Wx, WxT, H, H);
  for (int k = 0; k < 3; ++k)
    k_transpose<<<(H * H + 255) / 256, 256, 0, stream>>>(Wls + k * H * H, WlsT + k * H * H, H, H);
  k_transpose<<<(NOUT * H + 255) / 256, 256, 0, stream>>>(Wout, WoutT, NOUT, H);
  k_f32_to_bf16<<<(3 * H * H + 255) / 256, 256, 0, stream>>>(Wl, Wlbf, 3 * H * H);

  // per-edge features (rbf + rbf_h) and per-triplet angle
  k_edge_feat<<<(E + 63) / 64, 256, 0, stream>>>(pos, esrc, edst, freq, Wr, br, rbfG, rbfh, E);
  if (T > 0)
    k_angle<<<(T + 255) / 256, 256, 0, stream>>>(pos, ii, jjv, kkv, angle, T);

  // h = x @ Wx^T  -> bf16
  k_gemm_nt<128, false, false, true><<<(N + 63) / 64, 256, 0, stream>>>(x, WxT, nullptr, hbf, N);

  // fused MFMA edge block -> segment sum into nodeA
  k_edge_mfma<<<(E + 127) / 128, 256, 0, stream>>>(hbf, rbfh, Wlbf, bl, rbfG, Wrbf,
                                                   esrc, edst, nodeA, E);

  // 3 swish layers + output projection (fp32)
  k_gemm_nt<128, true, true, false><<<(N + 63) / 64, 256, 0, stream>>>(nodeA, WlsT, bls, nodeB, N);
  k_gemm_nt<128, true, true, false><<<(N + 63) / 64, 256, 0, stream>>>(nodeB, WlsT + H * H, bls + H, nodeA, N);
  k_gemm_nt<128, true, true, false><<<(N + 63) / 64, 256, 0, stream>>>(nodeA, WlsT + 2 * H * H, bls + 2 * H, nodeB, N);
  k_gemm_nt<64, false, false, false><<<(N + 63) / 64, 256, 0, stream>>>(nodeB, WoutT, nullptr, P, N);
}

// Round 5
// 506.929 us; speedup vs baseline: 3.5893x; 1.1267x over previous
//
#include <hip/hip_runtime.h>
#include <hip/hip_bf16.h>
#include <math.h>

#define H   128
#define NR  6
#define NOUT 64

typedef __attribute__((ext_vector_type(8))) short short8;
typedef __attribute__((ext_vector_type(4))) float floatx4;

__device__ __forceinline__ float swishf(float z) {
  float t = __expf(-z);
  return z / (1.0f + t);
}

__device__ __forceinline__ ushort f2bf(float x) {
  __hip_bfloat16 b = __float2bfloat16(x);
  return *reinterpret_cast<ushort*>(&b);
}

__device__ __forceinline__ float bf2f(ushort u) {
  unsigned int v = ((unsigned int)u) << 16;
  return __uint_as_float(v);
}

// async 16B global->LDS (wave-uniform LDS base + lane*16)
__device__ __forceinline__ void async_copy16(const void* g, void* l) {
  __builtin_amdgcn_global_load_lds(
      (const __attribute__((address_space(1))) unsigned int*)g,
      (__attribute__((address_space(3))) unsigned int*)l, 16, 0, 0);
}

// ---------------- zero fills ----------------
__global__ void k_zero4(float4* __restrict__ p, int n4) {
  int i = blockIdx.x * blockDim.x + threadIdx.x;
  if (i < n4) p[i] = make_float4(0.f, 0.f, 0.f, 0.f);
}
__global__ void k_zeroi(int* __restrict__ p, int n) {
  int i = blockIdx.x * blockDim.x + threadIdx.x;
  if (i < n) p[i] = 0;
}

// ---------------- fp32 -> bf16 convert ----------------
__global__ void k_f32_to_bf16(const float* __restrict__ in, ushort* __restrict__ out, int n) {
  int i = blockIdx.x * blockDim.x + threadIdx.x;
  if (i < n) out[i] = f2bf(in[i]);
}

// ---------------- fp32 -> (hi,lo) bf16 split ----------------
__global__ void k_split_bf16(const float* __restrict__ in, ushort* __restrict__ hi,
                             ushort* __restrict__ lo, int n) {
  int i = blockIdx.x * blockDim.x + threadIdx.x;
  if (i >= n) return;
  float x = in[i];
  ushort h = f2bf(x);
  hi[i] = h;
  lo[i] = f2bf(x - bf2f(h));
}

// ---------------- counting sort by dst: hist / scan / scatter ----------------
__global__ void k_hist(const int* __restrict__ dst, int* __restrict__ cnt, int E) {
  int i = blockIdx.x * blockDim.x + threadIdx.x;
  if (i < E) atomicAdd(&cnt[dst[i]], 1);
}

__global__ __launch_bounds__(1024) void k_scan(const int* __restrict__ cnt,
                                               int* __restrict__ cur, int N) {
  __shared__ int part[1024];
  const int tid = threadIdx.x;
  const int chunk = (N + 1023) / 1024;
  int lo = tid * chunk, hi = min(lo + chunk, N);
  int s = 0;
  for (int i = lo; i < hi; ++i) s += cnt[i];
  part[tid] = s;
  __syncthreads();
  if (tid == 0) {
    int run = 0;
    for (int i = 0; i < 1024; ++i) { int v = part[i]; part[i] = run; run += v; }
  }
  __syncthreads();
  int run = part[tid];
  for (int i = lo; i < hi; ++i) { int v = cnt[i]; cur[i] = run; run += v; }
}

__global__ void k_scatter(const int* __restrict__ dst, int* __restrict__ cur,
                          int* __restrict__ perm, int E) {
  int i = blockIdx.x * blockDim.x + threadIdx.x;
  if (i >= E) return;
  int p = atomicAdd(&cur[dst[i]], 1);
  perm[p] = i;
}

// ---------------- per-edge features in SORTED order ----------------
// sorted pos p -> original edge perm[p]; writes rbfG[p], rbfh[p], ssrc[p], sdst[p].
__global__ __launch_bounds__(256) void k_edge_feat(
    const float* __restrict__ pos, const int* __restrict__ esrc,
    const int* __restrict__ edst, const float* __restrict__ freq,
    const float* __restrict__ Wr,   // [128][6]
    const float* __restrict__ br,   // [128]
    const int* __restrict__ perm,
    float* __restrict__ rbfG,       // [E][6]
    ushort* __restrict__ rbfh,      // [E][128] bf16
    int* __restrict__ ssrc, int* __restrict__ sdst,
    int E) {
  __shared__ float wrS[128][6];
  __shared__ float brS[128];
  const int tid = threadIdx.x;
  for (int idx = tid; idx < 128 * 6; idx += 256) wrS[idx / 6][idx % 6] = Wr[idx];
  if (tid < 128) brS[tid] = br[tid];
  __syncthreads();

  const int p = blockIdx.x * 64 + (tid >> 2);
  if (p >= E) return;
  const int cg = (tid & 3) * 32;

  const int e = perm[p];
  const int s = esrc[e], d = edst[e];
  float dx = pos[d * 3 + 0] - pos[s * 3 + 0];
  float dy = pos[d * 3 + 1] - pos[s * 3 + 1];
  float dz = pos[d * 3 + 2] - pos[s * 3 + 2];
  float dist = sqrtf(dx * dx + dy * dy + dz * dz);
  float dn = dist * 0.2f;
  float inv = 1.0f / dn;
  float dn2 = dn * dn;
  float dp = dn2 * dn2 * dn;  // dn^5
  float env = inv - 21.0f * dp + 35.0f * dp * dn - 15.0f * dp * dn2;
  float rb[NR];
#pragma unroll
  for (int r = 0; r < NR; ++r) rb[r] = env * sinf(freq[r] * dn);

  if ((tid & 3) == 0) {
#pragma unroll
    for (int r = 0; r < NR; ++r) rbfG[(size_t)p * NR + r] = rb[r];
    ssrc[p] = s;
    sdst[p] = d;
  }

#pragma unroll
  for (int q = 0; q < 4; ++q) {
    short8 pk;
#pragma unroll
    for (int j = 0; j < 8; ++j) {
      int c = cg + q * 8 + j;
      float z = brS[c];
#pragma unroll
      for (int r = 0; r < NR; ++r) z += rb[r] * wrS[c][r];
      pk[j] = (short)f2bf(swishf(z));
    }
    *(short8*)(rbfh + (size_t)p * H + cg + q * 8) = pk;
  }
}

// ---------------- triplet angles ----------------
__global__ void k_angle(const float* __restrict__ pos, const int* __restrict__ ii,
                        const int* __restrict__ jj, const int* __restrict__ kk,
                        float* __restrict__ out, int T) {
  int t = blockIdx.x * blockDim.x + threadIdx.x;
  if (t >= T) return;
  int i = ii[t], j = jj[t], k = kk[t];
  float pix = pos[i * 3], piy = pos[i * 3 + 1], piz = pos[i * 3 + 2];
  float vjx = pos[j * 3] - pix, vjy = pos[j * 3 + 1] - piy, vjz = pos[j * 3 + 2] - piz;
  float vkx = pos[k * 3] - pix, vky = pos[k * 3 + 1] - piy, vkz = pos[k * 3 + 2] - piz;
  float a = vjx * vkx + vjy * vky + vjz * vkz;
  float cx = vjy * vkz - vjz * vky;
  float cy = vjz * vkx - vjx * vkz;
  float cz = vjx * vky - vjy * vkx;
  float b = sqrtf(cx * cx + cy * cy + cz * cz);
  out[t] = atan2f(b, a);
}

// ---------------- split-precision MFMA GEMM ----------------
// C[M,NT] = act(A[M,128] @ B[NT,128]^T + bias), A fp32 split on the fly into
// hi/lo bf16, B pre-split. acc = Ah*Bh + Ah*Bl + Al*Bh (fp32 accum) ~ fp32.
// Tile: 128 rows x NT cols, K-chunks of 32. Swizzle slot(row,g) = row*4 + (g ^ ((row>>1)&3)).
template <int NT, bool SWISH, bool BIAS, bool OBF>
__global__ __launch_bounds__(256) void k_gemm_split(
    const float* __restrict__ A,
    const ushort* __restrict__ Bhi,   // [NT][128] bf16
    const ushort* __restrict__ Blo,   // [NT][128] bf16
    const float* __restrict__ bias,   // [NT] or null
    void* __restrict__ C,             // [M][NT] fp32 or bf16
    int M) {
  constexpr int NJ = (NT == 128) ? 4 : 2;      // 16-col tiles per wave
  __shared__ ushort Ah[128 * 32];
  __shared__ ushort Al[128 * 32];
  __shared__ ushort Bh[NT * 32];
  __shared__ ushort Bl[NT * 32];

  const int tid = threadIdx.x;
  const int m0 = blockIdx.x * 128;
  const int w = tid >> 6;
  const int lane = tid & 63;
  const int l15 = lane & 15, quad = lane >> 4;
  const int wm = (w >> 1) * 64;
  const int wn = (w & 1) * (NT / 2);

  floatx4 acc[4][NJ];
#pragma unroll
  for (int i = 0; i < 4; ++i)
#pragma unroll
    for (int j = 0; j < NJ; ++j) acc[i][j] = floatx4{0.f, 0.f, 0.f, 0.f};

  for (int c = 0; c < 4; ++c) {
    const int kb = c * 32;
    // ---- A: manual load fp32 -> split into hi/lo planes ----
#pragma unroll
    for (int it = 0; it < 2; ++it) {
      int u = it * 256 + tid;             // 0..511
      int row = u >> 2, g = u & 3;
      int m = m0 + row;
      float4 v0 = make_float4(0.f, 0.f, 0.f, 0.f), v1 = v0;
      if (m < M) {
        v0 = *(const float4*)&A[(size_t)m * 128 + kb + g * 8];
        v1 = *(const float4*)&A[(size_t)m * 128 + kb + g * 8 + 4];
      }
      float xs[8] = {v0.x, v0.y, v0.z, v0.w, v1.x, v1.y, v1.z, v1.w};
      short8 hi, lo;
#pragma unroll
      for (int j = 0; j < 8; ++j) {
        ushort h = f2bf(xs[j]);
        hi[j] = (short)h;
        lo[j] = (short)f2bf(xs[j] - bf2f(h));
      }
      int slot = row * 4 + (g ^ ((row >> 1) & 3));
      *(short8*)(Ah + slot * 8) = hi;
      *(short8*)(Al + slot * 8) = lo;
    }
    // ---- B: async 16B/lane, inverse-swizzled global address ----
#pragma unroll
    for (int it = 0; it < (NT * 4) / 256; ++it) {
      int ub = it * 256 + w * 64;         // wave-uniform slot base
      int s = ub + lane;
      int row = s >> 2, gp = s & 3;
      int g = gp ^ ((row >> 1) & 3);
      int lb = __builtin_amdgcn_readfirstlane(ub);
      async_copy16((const void*)(Bhi + (size_t)row * 128 + kb + g * 8), (void*)(Bh + lb * 8));
      async_copy16((const void*)(Blo + (size_t)row * 128 + kb + g * 8), (void*)(Bl + lb * 8));
    }
    __syncthreads();
    // ---- MFMA (one K-step of 32 per chunk) ----
    short8 ah[4], al[4], bh[NJ], blv[NJ];
#pragma unroll
    for (int i = 0; i < 4; ++i) {
      int m = wm + i * 16 + l15;
      int slot = m * 4 + (quad ^ ((m >> 1) & 3));
      ah[i] = *(const short8*)(Ah + slot * 8);
      al[i] = *(const short8*)(Al + slot * 8);
    }
#pragma unroll
    for (int j = 0; j < NJ; ++j) {
      int n = wn + j * 16 + l15;
      int slot = n * 4 + (quad ^ ((n >> 1) & 3));
      bh[j] = *(const short8*)(Bh + slot * 8);
      blv[j] = *(const short8*)(Bl + slot * 8);
    }
#pragma unroll
    for (int i = 0; i < 4; ++i)
#pragma unroll
      for (int j = 0; j < NJ; ++j) {
        acc[i][j] = __builtin_amdgcn_mfma_f32_16x16x32_bf16(ah[i], bh[j], acc[i][j], 0, 0, 0);
        acc[i][j] = __builtin_amdgcn_mfma_f32_16x16x32_bf16(ah[i], blv[j], acc[i][j], 0, 0, 0);
        acc[i][j] = __builtin_amdgcn_mfma_f32_16x16x32_bf16(al[i], bh[j], acc[i][j], 0, 0, 0);
      }
    __syncthreads();
  }

  // ---- epilogue ----
#pragma unroll
  for (int i = 0; i < 4; ++i)
#pragma unroll
    for (int r = 0; r < 4; ++r) {
      int m = m0 + wm + i * 16 + quad * 4 + r;
      if (m < M) {
#pragma unroll
        for (int j = 0; j < NJ; ++j) {
          int n = wn + j * 16 + l15;
          float z = acc[i][j][r];
          if (BIAS) z += bias[n];
          if (SWISH) z = swishf(z);
          if (OBF) ((ushort*)C)[(size_t)m * NT + n] = f2bf(z);
          else     ((float*)C)[(size_t)m * NT + n] = z;
        }
      }
    }
}

// ---------------- MFMA fused edge block (sorted edges, segmented reduction) ----------------
__global__ __launch_bounds__(256, 4) void k_edge_mfma(
    const ushort* __restrict__ hbf,    // [N][128] bf16
    const ushort* __restrict__ rbfh,   // [E][128] bf16 (sorted order)
    const ushort* __restrict__ Wlbf,   // [128][384] bf16
    const float* __restrict__ bl,      // [128]
    const float* __restrict__ rbfG,    // [E][6] (sorted order)
    const float* __restrict__ Wrbf,    // [128][6]
    const int* __restrict__ ssrc, const int* __restrict__ sdst,  // sorted by dst
    float* __restrict__ node,          // [N,128]
    int E) {
  __shared__ ushort ABs[2 * 128 * 64 + 256];  // As | Bs, aliased as fp32 redS[128][65]
  __shared__ float rbfS[128][6];
  __shared__ int dstS[128];
  __shared__ int srcS[128];
  __shared__ float blS[128];

  ushort* As = ABs;
  ushort* Bs = ABs + 128 * 64;

  const int tid = threadIdx.x;
  const int e0 = blockIdx.x * 128;

  if (tid < 128) {
    int e = min(e0 + tid, E - 1);
    dstS[tid] = sdst[e];
    srcS[tid] = ssrc[e];
    blS[tid] = bl[tid];
  }
  for (int idx = tid; idx < 128 * NR; idx += 256) {
    int gidx = e0 * NR + idx;
    ((float*)rbfS)[idx] = (gidx < E * NR) ? rbfG[gidx] : 0.f;
  }
  __syncthreads();

  const int w = tid >> 6;
  const int lane = tid & 63;
  const int l15 = lane & 15, quad = lane >> 4;
  const int wm = (w >> 1) * 64;
  const int wn = (w & 1) * 64;
  const int wslot = w * 256;

  floatx4 acc[4][4];
#pragma unroll
  for (int i = 0; i < 4; ++i)
#pragma unroll
    for (int j = 0; j < 4; ++j) acc[i][j] = floatx4{0.f, 0.f, 0.f, 0.f};

  const int Em1 = E - 1;

  for (int c = 0; c < 6; ++c) {
    {
      const int* rowS = (c < 2) ? dstS : ((c < 4) ? srcS : nullptr);
      const ushort* base = (c < 4) ? hbf : rbfh;
      const int off = (c & 1) * 64;
#pragma unroll
      for (int i = 0; i < 4; ++i) {
        int u = wslot + i * 64 + lane;
        int nrow = u >> 3, gp = u & 7;
        int g = gp ^ (nrow & 7);
        int row = rowS ? rowS[nrow] : min(e0 + nrow, Em1);
        const ushort* gsrc = base + (size_t)row * H + off + g * 8;
        int lb = __builtin_amdgcn_readfirstlane(wslot + i * 64);
        async_copy16((const void*)gsrc, (void*)(As + lb * 8));
      }
    }
    {
#pragma unroll
      for (int i = 0; i < 4; ++i) {
        int u = wslot + i * 64 + lane;
        int nrow = u >> 3, gp = u & 7;
        int g = gp ^ (nrow & 7);
        const ushort* gsrc = Wlbf + (size_t)nrow * 384 + c * 64 + g * 8;
        int lb = __builtin_amdgcn_readfirstlane(wslot + i * 64);
        async_copy16((const void*)gsrc, (void*)(Bs + lb * 8));
      }
    }
    __syncthreads();
#pragma unroll
    for (int s = 0; s < 2; ++s) {
      const int gg = s * 4 + quad;
      short8 af[4], bfr[4];
#pragma unroll
      for (int i = 0; i < 4; ++i) {
        int m = wm + i * 16 + l15;
        af[i] = *(const short8*)(As + (m * 8 + (gg ^ (m & 7))) * 8);
      }
#pragma unroll
      for (int j = 0; j < 4; ++j) {
        int n = wn + j * 16 + l15;
        bfr[j] = *(const short8*)(Bs + (n * 8 + (gg ^ (n & 7))) * 8);
      }
#pragma unroll
      for (int i = 0; i < 4; ++i)
#pragma unroll
        for (int j = 0; j < 4; ++j)
          acc[i][j] = __builtin_amdgcn_mfma_f32_16x16x32_bf16(af[i], bfr[j], acc[i][j], 0, 0, 0);
    }
    __syncthreads();
  }

  // ---- epilogue: t = swish(z+bl) * (rbf . Wrbf[n]); segmented sum over sorted dst ----
  float* redS = (float*)ABs;   // [128][65]
  float wt[4][NR], blv[4];
#pragma unroll
  for (int j = 0; j < 4; ++j) {
    int n = wn + j * 16 + l15;
    blv[j] = blS[n];
#pragma unroll
    for (int r = 0; r < NR; ++r) wt[j][r] = Wrbf[n * NR + r];
  }

  for (int half = 0; half < 2; ++half) {
    __syncthreads();
    if ((w & 1) == half) {
#pragma unroll
      for (int i = 0; i < 4; ++i)
#pragma unroll
        for (int r = 0; r < 4; ++r) {
          int m = wm + i * 16 + quad * 4 + r;
          float rb[NR];
#pragma unroll
          for (int q = 0; q < NR; ++q) rb[q] = rbfS[m][q];
#pragma unroll
          for (int j = 0; j < 4; ++j) {
            float z = acc[i][j][r] + blv[j];
            float ev = swishf(z);
            float wv = 0.f;
#pragma unroll
            for (int q = 0; q < NR; ++q) wv += rb[q] * wt[j][q];
            redS[m * 65 + j * 16 + l15] = ev * wv;   // zero when p>=E (rb==0)
          }
        }
    }
    __syncthreads();
    int cc = tid & 63, chunk = tid >> 6;
    int mstart = chunk * 32;
    float s = 0.f;
    int prev = dstS[mstart];
    for (int m = mstart; m < mstart + 32; ++m) {
      int d = dstS[m];
      float v = redS[m * 65 + cc];
      if (d != prev) {
        atomicAdd(&node[(size_t)prev * H + half * 64 + cc], s);
        s = 0.f;
        prev = d;
      }
      s += v;
    }
    atomicAdd(&node[(size_t)prev * H + half * 64 + cc], s);
  }
}

extern "C" void kernel_launch(void* const* d_in, const int* in_sizes, int n_in,
                              void* d_out, int out_size, void* d_ws, size_t ws_size,
                              hipStream_t stream) {
  const float* x    = (const float*)d_in[0];
  const float* pos  = (const float*)d_in[1];
  const float* freq = (const float*)d_in[2];
  const float* Wx   = (const float*)d_in[3];
  const float* Wr   = (const float*)d_in[4];
  const float* br   = (const float*)d_in[5];
  const float* Wl   = (const float*)d_in[6];
  const float* bl   = (const float*)d_in[7];
  const float* Wrbf = (const float*)d_in[8];
  const float* Wls  = (const float*)d_in[9];
  const float* bls  = (const float*)d_in[10];
  const float* Wout = (const float*)d_in[11];
  const int* esrc = (const int*)d_in[12];
  const int* edst = (const int*)d_in[13];
  const int* ii   = (const int*)d_in[14];
  const int* jjv  = (const int*)d_in[15];
  const int* kkv  = (const int*)d_in[16];

  const int N = in_sizes[0] / H;
  const int E = in_sizes[12];
  const int T = in_sizes[14];

  float* out   = (float*)d_out;
  float* P     = out;                       // [N,64]
  float* angle = out + (size_t)N * NOUT;    // [T]

  float* ws = (float*)d_ws;
  float* rbfG  = ws; ws += (size_t)E * NR;
  float* nodeA = ws; ws += (size_t)N * H;
  float* nodeB = ws; ws += (size_t)N * H;
  ushort* u = (ushort*)ws;
  ushort* hbf    = u; u += (size_t)N * H;
  ushort* Wlbf   = u; u += 3 * H * H;
  ushort* rbfh   = u; u += (size_t)E * H;
  ushort* Wxhi   = u; u += H * H;
  ushort* Wxlo   = u; u += H * H;
  ushort* Wlshi  = u; u += 3 * H * H;
  ushort* Wlslo  = u; u += 3 * H * H;
  ushort* Wouthi = u; u += NOUT * H;
  ushort* Woutlo = u; u += NOUT * H;
  int* ip = (int*)u;
  int* cnt   = ip; ip += N;
  int* cur   = ip; ip += N;
  int* perm  = ip; ip += E;
  int* ssrcA = ip; ip += E;
  int* sdstA = ip; ip += E;

  // zeros
  k_zeroi<<<(N + 255) / 256, 256, 0, stream>>>(cnt, N);
  k_zero4<<<(N * H / 4 + 255) / 256, 256, 0, stream>>>((float4*)nodeA, N * H / 4);

  // counting sort of edges by dst
  k_hist<<<(E + 255) / 256, 256, 0, stream>>>(edst, cnt, E);
  k_scan<<<1, 1024, 0, stream>>>(cnt, cur, N);
  k_scatter<<<(E + 255) / 256, 256, 0, stream>>>(edst, cur, perm, E);

  // weight converts / splits (tiny)
  k_f32_to_bf16<<<(3 * H * H + 255) / 256, 256, 0, stream>>>(Wl, Wlbf, 3 * H * H);
  k_split_bf16<<<(H * H + 255) / 256, 256, 0, stream>>>(Wx, Wxhi, Wxlo, H * H);
  k_split_bf16<<<(3 * H * H + 255) / 256, 256, 0, stream>>>(Wls, Wlshi, Wlslo, 3 * H * H);
  k_split_bf16<<<(NOUT * H + 255) / 256, 256, 0, stream>>>(Wout, Wouthi, Woutlo, NOUT * H);

  // per-edge features in sorted order; angles
  k_edge_feat<<<(E + 63) / 64, 256, 0, stream>>>(pos, esrc, edst, freq, Wr, br, perm,
                                                 rbfG, rbfh, ssrcA, sdstA, E);
  if (T > 0)
    k_angle<<<(T + 255) / 256, 256, 0, stream>>>(pos, ii, jjv, kkv, angle, T);

  // h = x @ Wx^T -> bf16 (split-precision MFMA)
  k_gemm_split<128, false, false, true><<<(N + 127) / 128, 256, 0, stream>>>(
      x, Wxhi, Wxlo, nullptr, hbf, N);

  // fused MFMA edge block -> segmented segment-sum into nodeA
  k_edge_mfma<<<(E + 127) / 128, 256, 0, stream>>>(hbf, rbfh, Wlbf, bl, rbfG, Wrbf,
                                                   ssrcA, sdstA, nodeA, E);

  // 3 swish layers + output projection (split-precision MFMA)
  k_gemm_split<128, true, true, false><<<(N + 127) / 128, 256, 0, stream>>>(
      nodeA, Wlshi, Wlslo, bls, nodeB, N);
  k_gemm_split<128, true, true, false><<<(N + 127) / 128, 256, 0, stream>>>(
      nodeB, Wlshi + H * H, Wlslo + H * H, bls + H, nodeA, N);
  k_gemm_split<128, true, true, false><<<(N + 127) / 128, 256, 0, stream>>>(
      nodeA, Wlshi + 2 * H * H, Wlslo + 2 * H * H, bls + 2 * H, nodeB, N);
  k_gemm_split<64, false, false, false><<<(N + 127) / 128, 256, 0, stream>>>(
      nodeB, Wouthi, Woutlo, nullptr, P, N);
}

// Round 6
// 496.657 us; speedup vs baseline: 3.6635x; 1.0207x over previous
//
#include <hip/hip_runtime.h>
#include <hip/hip_bf16.h>
#include <math.h>

#define H   128
#define NR  6
#define NOUT 64

typedef __attribute__((ext_vector_type(8))) short short8;
typedef __attribute__((ext_vector_type(4))) float floatx4;

__device__ __forceinline__ float swishf(float z) {
  float t = __expf(-z);
  return z / (1.0f + t);
}

__device__ __forceinline__ ushort f2bf(float x) {
  __hip_bfloat16 b = __float2bfloat16(x);
  return *reinterpret_cast<ushort*>(&b);
}

__device__ __forceinline__ float bf2f(ushort u) {
  unsigned int v = ((unsigned int)u) << 16;
  return __uint_as_float(v);
}

// async 16B global->LDS (wave-uniform LDS base + lane*16)
__device__ __forceinline__ void async_copy16(const void* g, void* l) {
  __builtin_amdgcn_global_load_lds(
      (const __attribute__((address_space(1))) unsigned int*)g,
      (__attribute__((address_space(3))) unsigned int*)l, 16, 0, 0);
}

// ---------------- zero init (nodeA + cnt) ----------------
__global__ void k_zeroinit(float4* __restrict__ nodeA, int n4, int* __restrict__ cnt, int n) {
  int i = blockIdx.x * blockDim.x + threadIdx.x;
  if (i < n4) nodeA[i] = make_float4(0.f, 0.f, 0.f, 0.f);
  if (i < n) cnt[i] = 0;
}

// ---------------- merged weight conversion ----------------
__global__ void k_prep(const float* __restrict__ Wl, const float* __restrict__ Wx,
                       const float* __restrict__ Wls, const float* __restrict__ Wout,
                       ushort* __restrict__ Wlbf,
                       ushort* __restrict__ Wxhi, ushort* __restrict__ Wxlo,
                       ushort* __restrict__ Wlshi, ushort* __restrict__ Wlslo,
                       ushort* __restrict__ Wouthi, ushort* __restrict__ Woutlo) {
  int idx = blockIdx.x * blockDim.x + threadIdx.x;
  if (idx < 49152) {
    Wlbf[idx] = f2bf(Wl[idx]);
    return;
  }
  idx -= 49152;
  if (idx < 16384) {
    float x = Wx[idx];
    ushort h = f2bf(x);
    Wxhi[idx] = h; Wxlo[idx] = f2bf(x - bf2f(h));
    return;
  }
  idx -= 16384;
  if (idx < 49152) {
    float x = Wls[idx];
    ushort h = f2bf(x);
    Wlshi[idx] = h; Wlslo[idx] = f2bf(x - bf2f(h));
    return;
  }
  idx -= 49152;
  if (idx < 8192) {
    float x = Wout[idx];
    ushort h = f2bf(x);
    Wouthi[idx] = h; Woutlo[idx] = f2bf(x - bf2f(h));
  }
}

// ---------------- counting sort by dst: hist / scan / scatter ----------------
__global__ void k_hist(const int* __restrict__ dst, int* __restrict__ cnt, int E) {
  int i = blockIdx.x * blockDim.x + threadIdx.x;
  if (i < E) atomicAdd(&cnt[dst[i]], 1);
}

__global__ __launch_bounds__(1024) void k_scan(const int* __restrict__ cnt,
                                               int* __restrict__ cur, int N) {
  __shared__ int part[1024];
  const int tid = threadIdx.x;
  const int chunk = (N + 1023) / 1024;
  int lo = tid * chunk, hi = min(lo + chunk, N);
  int s = 0;
  for (int i = lo; i < hi; ++i) s += cnt[i];
  part[tid] = s;
  __syncthreads();
  if (tid == 0) {
    int run = 0;
    for (int i = 0; i < 1024; ++i) { int v = part[i]; part[i] = run; run += v; }
  }
  __syncthreads();
  int run = part[tid];
  for (int i = lo; i < hi; ++i) { int v = cnt[i]; cur[i] = run; run += v; }
}

__global__ void k_scatter(const int* __restrict__ dst, int* __restrict__ cur,
                          int* __restrict__ perm, int E) {
  int i = blockIdx.x * blockDim.x + threadIdx.x;
  if (i >= E) return;
  int p = atomicAdd(&cur[dst[i]], 1);
  perm[p] = i;
}

// ---------------- per-edge features in SORTED order ----------------
__global__ __launch_bounds__(256) void k_edge_feat(
    const float* __restrict__ pos, const int* __restrict__ esrc,
    const int* __restrict__ edst, const float* __restrict__ freq,
    const float* __restrict__ Wr,   // [128][6]
    const float* __restrict__ br,   // [128]
    const int* __restrict__ perm,
    float* __restrict__ rbfG,       // [E][6] sorted
    ushort* __restrict__ rbfh,      // [E][128] bf16 sorted
    int* __restrict__ ssrc, int* __restrict__ sdst,
    int E) {
  __shared__ float wrS[128][6];
  __shared__ float brS[128];
  const int tid = threadIdx.x;
  for (int idx = tid; idx < 128 * 6; idx += 256) wrS[idx / 6][idx % 6] = Wr[idx];
  if (tid < 128) brS[tid] = br[tid];
  __syncthreads();

  const int p = blockIdx.x * 64 + (tid >> 2);
  if (p >= E) return;
  const int cg = (tid & 3) * 32;

  const int e = perm[p];
  const int s = esrc[e], d = edst[e];
  float dx = pos[d * 3 + 0] - pos[s * 3 + 0];
  float dy = pos[d * 3 + 1] - pos[s * 3 + 1];
  float dz = pos[d * 3 + 2] - pos[s * 3 + 2];
  float dist = sqrtf(dx * dx + dy * dy + dz * dz);
  float dn = dist * 0.2f;
  float inv = 1.0f / dn;
  float dn2 = dn * dn;
  float dp = dn2 * dn2 * dn;  // dn^5
  float env = inv - 21.0f * dp + 35.0f * dp * dn - 15.0f * dp * dn2;
  float rb[NR];
#pragma unroll
  for (int r = 0; r < NR; ++r) rb[r] = env * sinf(freq[r] * dn);

  if ((tid & 3) == 0) {
#pragma unroll
    for (int r = 0; r < NR; ++r) rbfG[(size_t)p * NR + r] = rb[r];
    ssrc[p] = s;
    sdst[p] = d;
  }

#pragma unroll
  for (int q = 0; q < 4; ++q) {
    short8 pk;
#pragma unroll
    for (int j = 0; j < 8; ++j) {
      int c = cg + q * 8 + j;
      float z = brS[c];
#pragma unroll
      for (int r = 0; r < NR; ++r) z += rb[r] * wrS[c][r];
      pk[j] = (short)f2bf(swishf(z));
    }
    *(short8*)(rbfh + (size_t)p * H + cg + q * 8) = pk;
  }
}

// ---------------- triplet angles ----------------
__global__ void k_angle(const float* __restrict__ pos, const int* __restrict__ ii,
                        const int* __restrict__ jj, const int* __restrict__ kk,
                        float* __restrict__ out, int T) {
  int t = blockIdx.x * blockDim.x + threadIdx.x;
  if (t >= T) return;
  int i = ii[t], j = jj[t], k = kk[t];
  float pix = pos[i * 3], piy = pos[i * 3 + 1], piz = pos[i * 3 + 2];
  float vjx = pos[j * 3] - pix, vjy = pos[j * 3 + 1] - piy, vjz = pos[j * 3 + 2] - piz;
  float vkx = pos[k * 3] - pix, vky = pos[k * 3 + 1] - piy, vkz = pos[k * 3 + 2] - piz;
  float a = vjx * vkx + vjy * vky + vjz * vkz;
  float cx = vjy * vkz - vjz * vky;
  float cy = vjz * vkx - vjx * vkz;
  float cz = vjx * vky - vjy * vkx;
  float b = sqrtf(cx * cx + cy * cy + cz * cz);
  out[t] = atan2f(b, a);
}

// ---------------- split-precision MFMA GEMM, 64-row tiles ----------------
// C[M,NT] = act(A[M,128] @ B[NT,128]^T + bias). A split hi/lo on the fly.
template <int NT, bool SWISH, bool BIAS, bool OBF>
__global__ __launch_bounds__(256) void k_gemm_split(
    const float* __restrict__ A,
    const ushort* __restrict__ Bhi,   // [NT][128]
    const ushort* __restrict__ Blo,
    const float* __restrict__ bias,
    void* __restrict__ C,
    int M) {
  constexpr int NJ = NT / 32;
  __shared__ alignas(16) ushort Ah[64 * 32];
  __shared__ alignas(16) ushort Al[64 * 32];
  __shared__ alignas(16) ushort Bh[NT * 32];
  __shared__ alignas(16) ushort Bl[NT * 32];

  const int tid = threadIdx.x;
  const int m0 = blockIdx.x * 64;
  const int w = tid >> 6, lane = tid & 63;
  const int l15 = lane & 15, quad = lane >> 4;
  const int wm = (w >> 1) * 32;
  const int wn = (w & 1) * (NT / 2);

  floatx4 acc[2][NJ];
#pragma unroll
  for (int i = 0; i < 2; ++i)
#pragma unroll
    for (int j = 0; j < NJ; ++j) acc[i][j] = floatx4{0.f, 0.f, 0.f, 0.f};

  for (int c = 0; c < 4; ++c) {
    const int kb = c * 32;
    // A: 256 slots, 1/thread: row = tid>>2, g = tid&3
    {
      int row = tid >> 2, g = tid & 3;
      int m = m0 + row;
      float4 v0 = make_float4(0.f, 0.f, 0.f, 0.f), v1 = v0;
      if (m < M) {
        v0 = *(const float4*)&A[(size_t)m * 128 + kb + g * 8];
        v1 = *(const float4*)&A[(size_t)m * 128 + kb + g * 8 + 4];
      }
      float xs[8] = {v0.x, v0.y, v0.z, v0.w, v1.x, v1.y, v1.z, v1.w};
      short8 hi, lo;
#pragma unroll
      for (int j = 0; j < 8; ++j) {
        ushort h = f2bf(xs[j]);
        hi[j] = (short)h;
        lo[j] = (short)f2bf(xs[j] - bf2f(h));
      }
      int slot = row * 4 + (g ^ ((row >> 1) & 3));
      *(short8*)(Ah + slot * 8) = hi;
      *(short8*)(Al + slot * 8) = lo;
    }
    // B: async, inverse-swizzled global address
#pragma unroll
    for (int it = 0; it < (NT * 4) / 256; ++it) {
      int ub = it * 256 + w * 64;
      int s = ub + lane;
      int brow = s >> 2, gp = s & 3;
      int gg = gp ^ ((brow >> 1) & 3);
      int lb = __builtin_amdgcn_readfirstlane(ub);
      async_copy16((const void*)(Bhi + (size_t)brow * 128 + kb + gg * 8), (void*)(Bh + lb * 8));
      async_copy16((const void*)(Blo + (size_t)brow * 128 + kb + gg * 8), (void*)(Bl + lb * 8));
    }
    __syncthreads();
    short8 ah[2], al[2], bh[NJ], blv[NJ];
#pragma unroll
    for (int i = 0; i < 2; ++i) {
      int m = wm + i * 16 + l15;
      int slot = m * 4 + (quad ^ ((m >> 1) & 3));
      ah[i] = *(const short8*)(Ah + slot * 8);
      al[i] = *(const short8*)(Al + slot * 8);
    }
#pragma unroll
    for (int j = 0; j < NJ; ++j) {
      int n = wn + j * 16 + l15;
      int slot = n * 4 + (quad ^ ((n >> 1) & 3));
      bh[j] = *(const short8*)(Bh + slot * 8);
      blv[j] = *(const short8*)(Bl + slot * 8);
    }
#pragma unroll
    for (int i = 0; i < 2; ++i)
#pragma unroll
      for (int j = 0; j < NJ; ++j) {
        acc[i][j] = __builtin_amdgcn_mfma_f32_16x16x32_bf16(ah[i], bh[j], acc[i][j], 0, 0, 0);
        acc[i][j] = __builtin_amdgcn_mfma_f32_16x16x32_bf16(ah[i], blv[j], acc[i][j], 0, 0, 0);
        acc[i][j] = __builtin_amdgcn_mfma_f32_16x16x32_bf16(al[i], bh[j], acc[i][j], 0, 0, 0);
      }
    __syncthreads();
  }

#pragma unroll
  for (int i = 0; i < 2; ++i)
#pragma unroll
    for (int r = 0; r < 4; ++r) {
      int m = m0 + wm + i * 16 + quad * 4 + r;
      if (m < M) {
#pragma unroll
        for (int j = 0; j < NJ; ++j) {
          int n = wn + j * 16 + l15;
          float z = acc[i][j][r];
          if (BIAS) z += bias[n];
          if (SWISH) z = swishf(z);
          if (OBF) ((ushort*)C)[(size_t)m * NT + n] = f2bf(z);
          else     ((float*)C)[(size_t)m * NT + n] = z;
        }
      }
    }
}

// ---------------- fused node MLP: 3x (swish o Wls) + Wout, one kernel ----------------
// 64 rows/block; activations live in LDS hi/lo bf16 planes between phases.
__global__ __launch_bounds__(256, 4) void k_node_mlp(
    const float* __restrict__ nodeA,   // [M][128]
    const ushort* __restrict__ Wlshi,  // [3][128][128]
    const ushort* __restrict__ Wlslo,
    const ushort* __restrict__ Wouthi, // [64][128]
    const ushort* __restrict__ Woutlo,
    const float* __restrict__ bls,     // [3][128]
    float* __restrict__ P,             // [M][64]
    int M) {
  __shared__ alignas(16) ushort AactH[64 * 16 * 8];  // 16 KB
  __shared__ alignas(16) ushort AactL[64 * 16 * 8];  // 16 KB
  __shared__ alignas(16) ushort Bh[128 * 4 * 8];     // 8 KB
  __shared__ alignas(16) ushort Bl[128 * 4 * 8];     // 8 KB
  __shared__ float blsS[3 * 128];

  const int tid = threadIdx.x;
  const int m0 = blockIdx.x * 64;
  const int w = tid >> 6, lane = tid & 63;
  const int l15 = lane & 15, quad = lane >> 4;
  const int wm = (w >> 1) * 32;
  const int wn = (w & 1) * 64;

  for (int i = tid; i < 3 * 128; i += 256) blsS[i] = bls[i];

  floatx4 acc[2][4];

  for (int p = 0; p < 3; ++p) {
    const ushort* Bhg = Wlshi + p * 128 * 128;
    const ushort* Blg = Wlslo + p * 128 * 128;
#pragma unroll
    for (int i = 0; i < 2; ++i)
#pragma unroll
      for (int j = 0; j < 4; ++j) acc[i][j] = floatx4{0.f, 0.f, 0.f, 0.f};

    for (int c = 0; c < 4; ++c) {
      const int kb = c * 32;
      // stage B chunk
#pragma unroll
      for (int it = 0; it < 2; ++it) {
        int ub = it * 256 + w * 64;
        int s = ub + lane;
        int brow = s >> 2, gp = s & 3;
        int gg = gp ^ ((brow >> 1) & 3);
        int lb = __builtin_amdgcn_readfirstlane(ub);
        async_copy16((const void*)(Bhg + (size_t)brow * 128 + kb + gg * 8), (void*)(Bh + lb * 8));
        async_copy16((const void*)(Blg + (size_t)brow * 128 + kb + gg * 8), (void*)(Bl + lb * 8));
      }
      __syncthreads();
      // A fragments
      short8 ah[2], al[2];
      if (p == 0) {
#pragma unroll
        for (int i = 0; i < 2; ++i) {
          int m = m0 + wm + i * 16 + l15;
          float4 v0 = make_float4(0.f, 0.f, 0.f, 0.f), v1 = v0;
          if (m < M) {
            v0 = *(const float4*)&nodeA[(size_t)m * 128 + kb + quad * 8];
            v1 = *(const float4*)&nodeA[(size_t)m * 128 + kb + quad * 8 + 4];
          }
          float xs[8] = {v0.x, v0.y, v0.z, v0.w, v1.x, v1.y, v1.z, v1.w};
#pragma unroll
          for (int j = 0; j < 8; ++j) {
            ushort hh = f2bf(xs[j]);
            ah[i][j] = (short)hh;
            al[i][j] = (short)f2bf(xs[j] - bf2f(hh));
          }
        }
      } else {
#pragma unroll
        for (int i = 0; i < 2; ++i) {
          int arow = wm + i * 16 + l15;
          int g16 = c * 4 + quad;
          int slot = arow * 16 + (g16 ^ (arow & 15));
          ah[i] = *(const short8*)(AactH + slot * 8);
          al[i] = *(const short8*)(AactL + slot * 8);
        }
      }
      short8 bh[4], blv[4];
#pragma unroll
      for (int j = 0; j < 4; ++j) {
        int n = wn + j * 16 + l15;
        int slot = n * 4 + (quad ^ ((n >> 1) & 3));
        bh[j] = *(const short8*)(Bh + slot * 8);
        blv[j] = *(const short8*)(Bl + slot * 8);
      }
#pragma unroll
      for (int i = 0; i < 2; ++i)
#pragma unroll
        for (int j = 0; j < 4; ++j) {
          acc[i][j] = __builtin_amdgcn_mfma_f32_16x16x32_bf16(ah[i], bh[j], acc[i][j], 0, 0, 0);
          acc[i][j] = __builtin_amdgcn_mfma_f32_16x16x32_bf16(ah[i], blv[j], acc[i][j], 0, 0, 0);
          acc[i][j] = __builtin_amdgcn_mfma_f32_16x16x32_bf16(al[i], bh[j], acc[i][j], 0, 0, 0);
        }
      __syncthreads();
    }
    // epilogue: swish -> split -> Aact planes
#pragma unroll
    for (int i = 0; i < 2; ++i)
#pragma unroll
      for (int r = 0; r < 4; ++r) {
        int row = wm + i * 16 + quad * 4 + r;
#pragma unroll
        for (int j = 0; j < 4; ++j) {
          int col = wn + j * 16 + l15;
          float z = acc[i][j][r] + blsS[p * 128 + col];
          z = swishf(z);
          ushort hh = f2bf(z);
          int slot = row * 16 + ((col >> 3) ^ (row & 15));
          AactH[slot * 8 + (col & 7)] = hh;
          AactL[slot * 8 + (col & 7)] = f2bf(z - bf2f(hh));
        }
      }
    __syncthreads();
  }

  // ---- phase 3: P = Aact @ Wout^T (NT=64) ----
  const int wn3 = (w & 1) * 32;
#pragma unroll
  for (int i = 0; i < 2; ++i)
#pragma unroll
    for (int j = 0; j < 2; ++j) acc[i][j] = floatx4{0.f, 0.f, 0.f, 0.f};

  for (int c = 0; c < 4; ++c) {
    const int kb = c * 32;
    {
      int ub = w * 64;
      int s = ub + lane;
      int brow = s >> 2, gp = s & 3;
      int gg = gp ^ ((brow >> 1) & 3);
      int lb = __builtin_amdgcn_readfirstlane(ub);
      async_copy16((const void*)(Wouthi + (size_t)brow * 128 + kb + gg * 8), (void*)(Bh + lb * 8));
      async_copy16((const void*)(Woutlo + (size_t)brow * 128 + kb + gg * 8), (void*)(Bl + lb * 8));
    }
    __syncthreads();
    short8 ah[2], al[2], bh[2], blv[2];
#pragma unroll
    for (int i = 0; i < 2; ++i) {
      int arow = wm + i * 16 + l15;
      int g16 = c * 4 + quad;
      int slot = arow * 16 + (g16 ^ (arow & 15));
      ah[i] = *(const short8*)(AactH + slot * 8);
      al[i] = *(const short8*)(AactL + slot * 8);
    }
#pragma unroll
    for (int j = 0; j < 2; ++j) {
      int n = wn3 + j * 16 + l15;
      int slot = n * 4 + (quad ^ ((n >> 1) & 3));
      bh[j] = *(const short8*)(Bh + slot * 8);
      blv[j] = *(const short8*)(Bl + slot * 8);
    }
#pragma unroll
    for (int i = 0; i < 2; ++i)
#pragma unroll
      for (int j = 0; j < 2; ++j) {
        acc[i][j] = __builtin_amdgcn_mfma_f32_16x16x32_bf16(ah[i], bh[j], acc[i][j], 0, 0, 0);
        acc[i][j] = __builtin_amdgcn_mfma_f32_16x16x32_bf16(ah[i], blv[j], acc[i][j], 0, 0, 0);
        acc[i][j] = __builtin_amdgcn_mfma_f32_16x16x32_bf16(al[i], bh[j], acc[i][j], 0, 0, 0);
      }
    __syncthreads();
  }
#pragma unroll
  for (int i = 0; i < 2; ++i)
#pragma unroll
    for (int r = 0; r < 4; ++r) {
      int m = m0 + wm + i * 16 + quad * 4 + r;
      if (m < M) {
#pragma unroll
        for (int j = 0; j < 2; ++j) {
          int n = wn3 + j * 16 + l15;
          P[(size_t)m * NOUT + n] = acc[i][j][r];
        }
      }
    }
}

// ---------------- MFMA fused edge block (sorted, segmented reduction, MFMA epilogue) ----------------
__global__ __launch_bounds__(256, 4) void k_edge_mfma(
    const ushort* __restrict__ hbf,    // [N][128] bf16
    const ushort* __restrict__ rbfh,   // [E][128] bf16 (sorted)
    const ushort* __restrict__ Wlbf,   // [128][384] bf16
    const float* __restrict__ bl,      // [128]
    const float* __restrict__ rbfG,    // [E][6] (sorted)
    const float* __restrict__ Wrbf,    // [128][6]
    const int* __restrict__ ssrc, const int* __restrict__ sdst,
    float* __restrict__ node,          // [N,128]
    int E) {
  __shared__ alignas(16) ushort ABs[2 * 128 * 64 + 256];  // As|Bs, aliased fp32 redS[128][65]
  __shared__ float rbfS[128][6];
  __shared__ int dstS[128];
  __shared__ int srcS[128];
  __shared__ float blS[128];

  ushort* As = ABs;
  ushort* Bs = ABs + 128 * 64;

  const int tid = threadIdx.x;
  const int e0 = blockIdx.x * 128;

  if (tid < 128) {
    int e = min(e0 + tid, E - 1);
    dstS[tid] = sdst[e];
    srcS[tid] = ssrc[e];
    blS[tid] = bl[tid];
  }
  for (int idx = tid; idx < 128 * NR; idx += 256) {
    int gidx = e0 * NR + idx;
    ((float*)rbfS)[idx] = (gidx < E * NR) ? rbfG[gidx] : 0.f;
  }
  __syncthreads();

  const int w = tid >> 6;
  const int lane = tid & 63;
  const int l15 = lane & 15, quad = lane >> 4;
  const int wm = (w >> 1) * 64;
  const int wn = (w & 1) * 64;
  const int wslot = w * 256;

  floatx4 acc[4][4];
#pragma unroll
  for (int i = 0; i < 4; ++i)
#pragma unroll
    for (int j = 0; j < 4; ++j) acc[i][j] = floatx4{0.f, 0.f, 0.f, 0.f};

  const int Em1 = E - 1;

  for (int c = 0; c < 6; ++c) {
    {
      const int* rowS = (c < 2) ? dstS : ((c < 4) ? srcS : nullptr);
      const ushort* base = (c < 4) ? hbf : rbfh;
      const int off = (c & 1) * 64;
#pragma unroll
      for (int i = 0; i < 4; ++i) {
        int u = wslot + i * 64 + lane;
        int nrow = u >> 3, gp = u & 7;
        int g = gp ^ (nrow & 7);
        int row = rowS ? rowS[nrow] : min(e0 + nrow, Em1);
        const ushort* gsrc = base + (size_t)row * H + off + g * 8;
        int lb = __builtin_amdgcn_readfirstlane(wslot + i * 64);
        async_copy16((const void*)gsrc, (void*)(As + lb * 8));
      }
    }
    {
#pragma unroll
      for (int i = 0; i < 4; ++i) {
        int u = wslot + i * 64 + lane;
        int nrow = u >> 3, gp = u & 7;
        int g = gp ^ (nrow & 7);
        const ushort* gsrc = Wlbf + (size_t)nrow * 384 + c * 64 + g * 8;
        int lb = __builtin_amdgcn_readfirstlane(wslot + i * 64);
        async_copy16((const void*)gsrc, (void*)(Bs + lb * 8));
      }
    }
    __syncthreads();
#pragma unroll
    for (int s = 0; s < 2; ++s) {
      const int gg = s * 4 + quad;
      short8 af[4], bfr[4];
#pragma unroll
      for (int i = 0; i < 4; ++i) {
        int m = wm + i * 16 + l15;
        af[i] = *(const short8*)(As + (m * 8 + (gg ^ (m & 7))) * 8);
      }
#pragma unroll
      for (int j = 0; j < 4; ++j) {
        int n = wn + j * 16 + l15;
        bfr[j] = *(const short8*)(Bs + (n * 8 + (gg ^ (n & 7))) * 8);
      }
#pragma unroll
      for (int i = 0; i < 4; ++i)
#pragma unroll
        for (int j = 0; j < 4; ++j)
          acc[i][j] = __builtin_amdgcn_mfma_f32_16x16x32_bf16(af[i], bfr[j], acc[i][j], 0, 0, 0);
    }
    __syncthreads();
  }

  // ---- epilogue: trbf via MFMA (K=6 zero-padded), then segmented sum ----
  float* redS = (float*)ABs;   // [128][65]
  float blv[4];
#pragma unroll
  for (int j = 0; j < 4; ++j) blv[j] = blS[wn + j * 16 + l15];

  short8 bfrw[4];
#pragma unroll
  for (int j = 0; j < 4; ++j) {
    short8 v = {0, 0, 0, 0, 0, 0, 0, 0};
    if (quad == 0) {
      int n = wn + j * 16 + l15;
#pragma unroll
      for (int q = 0; q < NR; ++q) v[q] = (short)f2bf(Wrbf[n * NR + q]);
    }
    bfrw[j] = v;
  }

  for (int half = 0; half < 2; ++half) {
    __syncthreads();
    if ((w & 1) == half) {
#pragma unroll
      for (int i = 0; i < 4; ++i) {
        short8 afr = {0, 0, 0, 0, 0, 0, 0, 0};
        if (quad == 0) {
          int m = wm + i * 16 + l15;
#pragma unroll
          for (int q = 0; q < NR; ++q) afr[q] = (short)f2bf(rbfS[m][q]);
        }
        floatx4 trb[4];
#pragma unroll
        for (int j = 0; j < 4; ++j)
          trb[j] = __builtin_amdgcn_mfma_f32_16x16x32_bf16(
              afr, bfrw[j], floatx4{0.f, 0.f, 0.f, 0.f}, 0, 0, 0);
#pragma unroll
        for (int r = 0; r < 4; ++r) {
          int m = wm + i * 16 + quad * 4 + r;
#pragma unroll
          for (int j = 0; j < 4; ++j) {
            float z = acc[i][j][r] + blv[j];
            redS[m * 65 + j * 16 + l15] = swishf(z) * trb[j][r];
          }
        }
      }
    }
    __syncthreads();
    int cc = tid & 63, chunk = tid >> 6;
    int mstart = chunk * 32;
    float s = 0.f;
    int prev = dstS[mstart];
    for (int m = mstart; m < mstart + 32; ++m) {
      int d = dstS[m];
      float v = redS[m * 65 + cc];
      if (d != prev) {
        atomicAdd(&node[(size_t)prev * H + half * 64 + cc], s);
        s = 0.f;
        prev = d;
      }
      s += v;
    }
    atomicAdd(&node[(size_t)prev * H + half * 64 + cc], s);
  }
}

extern "C" void kernel_launch(void* const* d_in, const int* in_sizes, int n_in,
                              void* d_out, int out_size, void* d_ws, size_t ws_size,
                              hipStream_t stream) {
  const float* x    = (const float*)d_in[0];
  const float* pos  = (const float*)d_in[1];
  const float* freq = (const float*)d_in[2];
  const float* Wx   = (const float*)d_in[3];
  const float* Wr   = (const float*)d_in[4];
  const float* br   = (const float*)d_in[5];
  const float* Wl   = (const float*)d_in[6];
  const float* bl   = (const float*)d_in[7];
  const float* Wrbf = (const float*)d_in[8];
  const float* Wls  = (const float*)d_in[9];
  const float* bls  = (const float*)d_in[10];
  const float* Wout = (const float*)d_in[11];
  const int* esrc = (const int*)d_in[12];
  const int* edst = (const int*)d_in[13];
  const int* ii   = (const int*)d_in[14];
  const int* jjv  = (const int*)d_in[15];
  const int* kkv  = (const int*)d_in[16];

  const int N = in_sizes[0] / H;
  const int E = in_sizes[12];
  const int T = in_sizes[14];

  float* out   = (float*)d_out;
  float* P     = out;                       // [N,64]
  float* angle = out + (size_t)N * NOUT;    // [T]

  float* ws = (float*)d_ws;
  float* rbfG  = ws; ws += (size_t)E * NR;
  float* nodeA = ws; ws += (size_t)N * H;
  ushort* u = (ushort*)ws;
  ushort* hbf    = u; u += (size_t)N * H;
  ushort* Wlbf   = u; u += 3 * H * H;
  ushort* rbfh   = u; u += (size_t)E * H;
  ushort* Wxhi   = u; u += H * H;
  ushort* Wxlo   = u; u += H * H;
  ushort* Wlshi  = u; u += 3 * H * H;
  ushort* Wlslo  = u; u += 3 * H * H;
  ushort* Wouthi = u; u += NOUT * H;
  ushort* Woutlo = u; u += NOUT * H;
  int* ip = (int*)u;
  int* cnt   = ip; ip += N;
  int* cur   = ip; ip += N;
  int* perm  = ip; ip += E;
  int* ssrcA = ip; ip += E;
  int* sdstA = ip; ip += E;

  // zeros (nodeA + cnt)
  {
    int n4 = N * H / 4;
    k_zeroinit<<<(n4 + 255) / 256, 256, 0, stream>>>((float4*)nodeA, n4, cnt, N);
  }

  // counting sort of edges by dst
  k_hist<<<(E + 255) / 256, 256, 0, stream>>>(edst, cnt, E);
  k_scan<<<1, 1024, 0, stream>>>(cnt, cur, N);
  k_scatter<<<(E + 255) / 256, 256, 0, stream>>>(edst, cur, perm, E);

  // merged weight converts/splits
  k_prep<<<(122880 + 255) / 256, 256, 0, stream>>>(Wl, Wx, Wls, Wout, Wlbf,
                                                   Wxhi, Wxlo, Wlshi, Wlslo, Wouthi, Woutlo);

  // per-edge features in sorted order; angles
  k_edge_feat<<<(E + 63) / 64, 256, 0, stream>>>(pos, esrc, edst, freq, Wr, br, perm,
                                                 rbfG, rbfh, ssrcA, sdstA, E);
  if (T > 0)
    k_angle<<<(T + 255) / 256, 256, 0, stream>>>(pos, ii, jjv, kkv, angle, T);

  // h = x @ Wx^T -> bf16 (split-precision MFMA, 64-row tiles)
  k_gemm_split<128, false, false, true><<<(N + 63) / 64, 256, 0, stream>>>(
      x, Wxhi, Wxlo, nullptr, hbf, N);

  // fused MFMA edge block -> segmented segment-sum into nodeA
  k_edge_mfma<<<(E + 127) / 128, 256, 0, stream>>>(hbf, rbfh, Wlbf, bl, rbfG, Wrbf,
                                                   ssrcA, sdstA, nodeA, E);

  // fused node MLP: 3 swish layers + output projection in one kernel
  k_node_mlp<<<(N + 63) / 64, 256, 0, stream>>>(nodeA, Wlshi, Wlslo, Wouthi, Woutlo,
                                                bls, P, N);
}

// Round 8
// 493.371 us; speedup vs baseline: 3.6879x; 1.0067x over previous
//
#include <hip/hip_runtime.h>
#include <hip/hip_bf16.h>
#include <math.h>

#define H   128
#define NR  6
#define NOUT 64

typedef __attribute__((ext_vector_type(8))) short short8;
typedef __attribute__((ext_vector_type(4))) float floatx4;

__device__ __forceinline__ float swishf(float z) {
  float t = __expf(-z);
  return z / (1.0f + t);
}

__device__ __forceinline__ ushort f2bf(float x) {
  __hip_bfloat16 b = __float2bfloat16(x);
  return *reinterpret_cast<ushort*>(&b);
}

__device__ __forceinline__ float bf2f(ushort u) {
  unsigned int v = ((unsigned int)u) << 16;
  return __uint_as_float(v);
}

// async 16B global->LDS (wave-uniform LDS base + lane*16)
__device__ __forceinline__ void async_copy16(const void* g, void* l) {
  __builtin_amdgcn_global_load_lds(
      (const __attribute__((address_space(1))) unsigned int*)g,
      (__attribute__((address_space(3))) unsigned int*)l, 16, 0, 0);
}

// ---------------- zero init (nodeA + cnt) ----------------
__global__ void k_zeroinit(float4* __restrict__ nodeA, int n4, int* __restrict__ cnt, int n) {
  int i = blockIdx.x * blockDim.x + threadIdx.x;
  if (i < n4) nodeA[i] = make_float4(0.f, 0.f, 0.f, 0.f);
  if (i < n) cnt[i] = 0;
}

// ---------------- merged weight conversion ----------------
__global__ void k_prep(const float* __restrict__ Wl, const float* __restrict__ Wx,
                       const float* __restrict__ Wls, const float* __restrict__ Wout,
                       ushort* __restrict__ Wlbf,
                       ushort* __restrict__ Wxhi, ushort* __restrict__ Wxlo,
                       ushort* __restrict__ Wlshi, ushort* __restrict__ Wlslo,
                       ushort* __restrict__ Wouthi, ushort* __restrict__ Woutlo) {
  int idx = blockIdx.x * blockDim.x + threadIdx.x;
  if (idx < 49152) {
    Wlbf[idx] = f2bf(Wl[idx]);
    return;
  }
  idx -= 49152;
  if (idx < 16384) {
    float x = Wx[idx];
    ushort h = f2bf(x);
    Wxhi[idx] = h; Wxlo[idx] = f2bf(x - bf2f(h));
    return;
  }
  idx -= 16384;
  if (idx < 49152) {
    float x = Wls[idx];
    ushort h = f2bf(x);
    Wlshi[idx] = h; Wlslo[idx] = f2bf(x - bf2f(h));
    return;
  }
  idx -= 49152;
  if (idx < 8192) {
    float x = Wout[idx];
    ushort h = f2bf(x);
    Wouthi[idx] = h; Woutlo[idx] = f2bf(x - bf2f(h));
  }
}

// ---------------- counting sort by dst: hist / scan / scatter ----------------
__global__ void k_hist(const int* __restrict__ dst, int* __restrict__ cnt, int E) {
  int i = blockIdx.x * blockDim.x + threadIdx.x;
  if (i < E) atomicAdd(&cnt[dst[i]], 1);
}

// parallel prefix: per-thread chunk sums -> wave shfl scan -> wave offsets -> write
__global__ __launch_bounds__(1024) void k_scan(const int* __restrict__ cnt,
                                               int* __restrict__ cur, int N) {
  __shared__ int wsum[16];
  const int tid = threadIdx.x;
  const int chunk = (N + 1023) / 1024;
  int lo = tid * chunk, hi = min(lo + chunk, N);
  int s = 0;
  for (int i = lo; i < hi; ++i) s += cnt[i];
  const int lane = tid & 63, wv = tid >> 6;
  int v = s;
#pragma unroll
  for (int off = 1; off < 64; off <<= 1) {
    int t = __shfl_up(v, off, 64);
    if (lane >= off) v += t;
  }
  if (lane == 63) wsum[wv] = v;
  __syncthreads();
  if (wv == 0 && lane < 16) {
    int t = wsum[lane];
#pragma unroll
    for (int off = 1; off < 16; off <<= 1) {
      int u2 = __shfl_up(t, off, 64);
      if (lane >= off) t += u2;
    }
    wsum[lane] = t;  // inclusive wave sums
  }
  __syncthreads();
  int base = (wv > 0 ? wsum[wv - 1] : 0) + (v - s);  // exclusive prefix for this thread
  int run = base;
  for (int i = lo; i < hi; ++i) { int c = cnt[i]; cur[i] = run; run += c; }
}

__global__ void k_scatter(const int* __restrict__ dst, int* __restrict__ cur,
                          int* __restrict__ perm, int E) {
  int i = blockIdx.x * blockDim.x + threadIdx.x;
  if (i >= E) return;
  int p = atomicAdd(&cur[dst[i]], 1);
  perm[p] = i;
}

// ---------------- per-edge features in SORTED order ----------------
__global__ __launch_bounds__(256) void k_edge_feat(
    const float* __restrict__ pos, const int* __restrict__ esrc,
    const int* __restrict__ edst, const float* __restrict__ freq,
    const float* __restrict__ Wr,   // [128][6]
    const float* __restrict__ br,   // [128]
    const int* __restrict__ perm,
    float* __restrict__ rbfG,       // [E][6] sorted
    ushort* __restrict__ rbfh,      // [E][128] bf16 sorted
    int* __restrict__ ssrc, int* __restrict__ sdst,
    int E) {
  __shared__ float wrS[128][6];
  __shared__ float brS[128];
  const int tid = threadIdx.x;
  for (int idx = tid; idx < 128 * 6; idx += 256) wrS[idx / 6][idx % 6] = Wr[idx];
  if (tid < 128) brS[tid] = br[tid];
  __syncthreads();

  const int p = blockIdx.x * 64 + (tid >> 2);
  if (p >= E) return;
  const int cg = (tid & 3) * 32;

  const int e = perm[p];
  const int s = esrc[e], d = edst[e];
  float dx = pos[d * 3 + 0] - pos[s * 3 + 0];
  float dy = pos[d * 3 + 1] - pos[s * 3 + 1];
  float dz = pos[d * 3 + 2] - pos[s * 3 + 2];
  float dist = sqrtf(dx * dx + dy * dy + dz * dz);
  float dn = dist * 0.2f;
  float inv = 1.0f / dn;
  float dn2 = dn * dn;
  float dp = dn2 * dn2 * dn;  // dn^5
  float env = inv - 21.0f * dp + 35.0f * dp * dn - 15.0f * dp * dn2;
  float rb[NR];
#pragma unroll
  for (int r = 0; r < NR; ++r) rb[r] = env * sinf(freq[r] * dn);

  if ((tid & 3) == 0) {
#pragma unroll
    for (int r = 0; r < NR; ++r) rbfG[(size_t)p * NR + r] = rb[r];
    ssrc[p] = s;
    sdst[p] = d;
  }

#pragma unroll
  for (int q = 0; q < 4; ++q) {
    short8 pk;
#pragma unroll
    for (int j = 0; j < 8; ++j) {
      int c = cg + q * 8 + j;
      float z = brS[c];
#pragma unroll
      for (int r = 0; r < NR; ++r) z += rb[r] * wrS[c][r];
      pk[j] = (short)f2bf(swishf(z));
    }
    *(short8*)(rbfh + (size_t)p * H + cg + q * 8) = pk;
  }
}

// ---------------- triplet angles ----------------
__global__ void k_angle(const float* __restrict__ pos, const int* __restrict__ ii,
                        const int* __restrict__ jj, const int* __restrict__ kk,
                        float* __restrict__ out, int T) {
  int t = blockIdx.x * blockDim.x + threadIdx.x;
  if (t >= T) return;
  int i = ii[t], j = jj[t], k = kk[t];
  float pix = pos[i * 3], piy = pos[i * 3 + 1], piz = pos[i * 3 + 2];
  float vjx = pos[j * 3] - pix, vjy = pos[j * 3 + 1] - piy, vjz = pos[j * 3 + 2] - piz;
  float vkx = pos[k * 3] - pix, vky = pos[k * 3 + 1] - piy, vkz = pos[k * 3 + 2] - piz;
  float a = vjx * vkx + vjy * vky + vjz * vkz;
  float cx = vjy * vkz - vjz * vky;
  float cy = vjz * vkx - vjx * vkz;
  float cz = vjx * vky - vjy * vkx;
  float b = sqrtf(cx * cx + cy * cy + cz * cz);
  out[t] = atan2f(b, a);
}

// ---------------- split-precision MFMA GEMM, 64-row tiles ----------------
template <int NT, bool SWISH, bool BIAS, bool OBF>
__global__ __launch_bounds__(256) void k_gemm_split(
    const float* __restrict__ A,
    const ushort* __restrict__ Bhi,   // [NT][128]
    const ushort* __restrict__ Blo,
    const float* __restrict__ bias,
    void* __restrict__ C,
    int M) {
  constexpr int NJ = NT / 32;
  __shared__ alignas(16) ushort Ah[64 * 32];
  __shared__ alignas(16) ushort Al[64 * 32];
  __shared__ alignas(16) ushort Bh[NT * 32];
  __shared__ alignas(16) ushort Bl[NT * 32];

  const int tid = threadIdx.x;
  const int m0 = blockIdx.x * 64;
  const int w = tid >> 6, lane = tid & 63;
  const int l15 = lane & 15, quad = lane >> 4;
  const int wm = (w >> 1) * 32;
  const int wn = (w & 1) * (NT / 2);

  floatx4 acc[2][NJ];
#pragma unroll
  for (int i = 0; i < 2; ++i)
#pragma unroll
    for (int j = 0; j < NJ; ++j) acc[i][j] = floatx4{0.f, 0.f, 0.f, 0.f};

  for (int c = 0; c < 4; ++c) {
    const int kb = c * 32;
    {
      int row = tid >> 2, g = tid & 3;
      int m = m0 + row;
      float4 v0 = make_float4(0.f, 0.f, 0.f, 0.f), v1 = v0;
      if (m < M) {
        v0 = *(const float4*)&A[(size_t)m * 128 + kb + g * 8];
        v1 = *(const float4*)&A[(size_t)m * 128 + kb + g * 8 + 4];
      }
      float xs[8] = {v0.x, v0.y, v0.z, v0.w, v1.x, v1.y, v1.z, v1.w};
      short8 hi, lo;
#pragma unroll
      for (int j = 0; j < 8; ++j) {
        ushort h = f2bf(xs[j]);
        hi[j] = (short)h;
        lo[j] = (short)f2bf(xs[j] - bf2f(h));
      }
      int slot = row * 4 + (g ^ ((row >> 1) & 3));
      *(short8*)(Ah + slot * 8) = hi;
      *(short8*)(Al + slot * 8) = lo;
    }
#pragma unroll
    for (int it = 0; it < (NT * 4) / 256; ++it) {
      int ub = it * 256 + w * 64;
      int s = ub + lane;
      int brow = s >> 2, gp = s & 3;
      int gg = gp ^ ((brow >> 1) & 3);
      int lb = __builtin_amdgcn_readfirstlane(ub);
      async_copy16((const void*)(Bhi + (size_t)brow * 128 + kb + gg * 8), (void*)(Bh + lb * 8));
      async_copy16((const void*)(Blo + (size_t)brow * 128 + kb + gg * 8), (void*)(Bl + lb * 8));
    }
    __syncthreads();
    short8 ah[2], al[2], bh[NJ], blv[NJ];
#pragma unroll
    for (int i = 0; i < 2; ++i) {
      int m = wm + i * 16 + l15;
      int slot = m * 4 + (quad ^ ((m >> 1) & 3));
      ah[i] = *(const short8*)(Ah + slot * 8);
      al[i] = *(const short8*)(Al + slot * 8);
    }
#pragma unroll
    for (int j = 0; j < NJ; ++j) {
      int n = wn + j * 16 + l15;
      int slot = n * 4 + (quad ^ ((n >> 1) & 3));
      bh[j] = *(const short8*)(Bh + slot * 8);
      blv[j] = *(const short8*)(Bl + slot * 8);
    }
#pragma unroll
    for (int i = 0; i < 2; ++i)
#pragma unroll
      for (int j = 0; j < NJ; ++j) {
        acc[i][j] = __builtin_amdgcn_mfma_f32_16x16x32_bf16(ah[i], bh[j], acc[i][j], 0, 0, 0);
        acc[i][j] = __builtin_amdgcn_mfma_f32_16x16x32_bf16(ah[i], blv[j], acc[i][j], 0, 0, 0);
        acc[i][j] = __builtin_amdgcn_mfma_f32_16x16x32_bf16(al[i], bh[j], acc[i][j], 0, 0, 0);
      }
    __syncthreads();
  }

#pragma unroll
  for (int i = 0; i < 2; ++i)
#pragma unroll
    for (int r = 0; r < 4; ++r) {
      int m = m0 + wm + i * 16 + quad * 4 + r;
      if (m < M) {
#pragma unroll
        for (int j = 0; j < NJ; ++j) {
          int n = wn + j * 16 + l15;
          float z = acc[i][j][r];
          if (BIAS) z += bias[n];
          if (SWISH) z = swishf(z);
          if (OBF) ((ushort*)C)[(size_t)m * NT + n] = f2bf(z);
          else     ((float*)C)[(size_t)m * NT + n] = z;
        }
      }
    }
}

// ---------------- fused node MLP: 3x (swish o Wls) + Wout ----------------
__global__ __launch_bounds__(256, 4) void k_node_mlp(
    const float* __restrict__ nodeA,   // [M][128]
    const ushort* __restrict__ Wlshi,  // [3][128][128]
    const ushort* __restrict__ Wlslo,
    const ushort* __restrict__ Wouthi, // [64][128]
    const ushort* __restrict__ Woutlo,
    const float* __restrict__ bls,     // [3][128]
    float* __restrict__ P,             // [M][64]
    int M) {
  __shared__ alignas(16) ushort AactH[64 * 16 * 8];
  __shared__ alignas(16) ushort AactL[64 * 16 * 8];
  __shared__ alignas(16) ushort Bh[128 * 4 * 8];
  __shared__ alignas(16) ushort Bl[128 * 4 * 8];
  __shared__ float blsS[3 * 128];

  const int tid = threadIdx.x;
  const int m0 = blockIdx.x * 64;
  const int w = tid >> 6, lane = tid & 63;
  const int l15 = lane & 15, quad = lane >> 4;
  const int wm = (w >> 1) * 32;
  const int wn = (w & 1) * 64;

  for (int i = tid; i < 3 * 128; i += 256) blsS[i] = bls[i];

  floatx4 acc[2][4];

  for (int p = 0; p < 3; ++p) {
    const ushort* Bhg = Wlshi + p * 128 * 128;
    const ushort* Blg = Wlslo + p * 128 * 128;
#pragma unroll
    for (int i = 0; i < 2; ++i)
#pragma unroll
      for (int j = 0; j < 4; ++j) acc[i][j] = floatx4{0.f, 0.f, 0.f, 0.f};

    for (int c = 0; c < 4; ++c) {
      const int kb = c * 32;
#pragma unroll
      for (int it = 0; it < 2; ++it) {
        int ub = it * 256 + w * 64;
        int s = ub + lane;
        int brow = s >> 2, gp = s & 3;
        int gg = gp ^ ((brow >> 1) & 3);
        int lb = __builtin_amdgcn_readfirstlane(ub);
        async_copy16((const void*)(Bhg + (size_t)brow * 128 + kb + gg * 8), (void*)(Bh + lb * 8));
        async_copy16((const void*)(Blg + (size_t)brow * 128 + kb + gg * 8), (void*)(Bl + lb * 8));
      }
      __syncthreads();
      short8 ah[2], al[2];
      if (p == 0) {
#pragma unroll
        for (int i = 0; i < 2; ++i) {
          int m = m0 + wm + i * 16 + l15;
          float4 v0 = make_float4(0.f, 0.f, 0.f, 0.f), v1 = v0;
          if (m < M) {
            v0 = *(const float4*)&nodeA[(size_t)m * 128 + kb + quad * 8];
            v1 = *(const float4*)&nodeA[(size_t)m * 128 + kb + quad * 8 + 4];
          }
          float xs[8] = {v0.x, v0.y, v0.z, v0.w, v1.x, v1.y, v1.z, v1.w};
#pragma unroll
          for (int j = 0; j < 8; ++j) {
            ushort hh = f2bf(xs[j]);
            ah[i][j] = (short)hh;
            al[i][j] = (short)f2bf(xs[j] - bf2f(hh));
          }
        }
      } else {
#pragma unroll
        for (int i = 0; i < 2; ++i) {
          int arow = wm + i * 16 + l15;
          int g16 = c * 4 + quad;
          int slot = arow * 16 + (g16 ^ (arow & 15));
          ah[i] = *(const short8*)(AactH + slot * 8);
          al[i] = *(const short8*)(AactL + slot * 8);
        }
      }
      short8 bh[4], blv[4];
#pragma unroll
      for (int j = 0; j < 4; ++j) {
        int n = wn + j * 16 + l15;
        int slot = n * 4 + (quad ^ ((n >> 1) & 3));
        bh[j] = *(const short8*)(Bh + slot * 8);
        blv[j] = *(const short8*)(Bl + slot * 8);
      }
#pragma unroll
      for (int i = 0; i < 2; ++i)
#pragma unroll
        for (int j = 0; j < 4; ++j) {
          acc[i][j] = __builtin_amdgcn_mfma_f32_16x16x32_bf16(ah[i], bh[j], acc[i][j], 0, 0, 0);
          acc[i][j] = __builtin_amdgcn_mfma_f32_16x16x32_bf16(ah[i], blv[j], acc[i][j], 0, 0, 0);
          acc[i][j] = __builtin_amdgcn_mfma_f32_16x16x32_bf16(al[i], bh[j], acc[i][j], 0, 0, 0);
        }
      __syncthreads();
    }
#pragma unroll
    for (int i = 0; i < 2; ++i)
#pragma unroll
      for (int r = 0; r < 4; ++r) {
        int row = wm + i * 16 + quad * 4 + r;
#pragma unroll
        for (int j = 0; j < 4; ++j) {
          int col = wn + j * 16 + l15;
          float z = acc[i][j][r] + blsS[p * 128 + col];
          z = swishf(z);
          ushort hh = f2bf(z);
          int slot = row * 16 + ((col >> 3) ^ (row & 15));
          AactH[slot * 8 + (col & 7)] = hh;
          AactL[slot * 8 + (col & 7)] = f2bf(z - bf2f(hh));
        }
      }
    __syncthreads();
  }

  const int wn3 = (w & 1) * 32;
#pragma unroll
  for (int i = 0; i < 2; ++i)
#pragma unroll
    for (int j = 0; j < 2; ++j) acc[i][j] = floatx4{0.f, 0.f, 0.f, 0.f};

  for (int c = 0; c < 4; ++c) {
    const int kb = c * 32;
    {
      int ub = w * 64;
      int s = ub + lane;
      int brow = s >> 2, gp = s & 3;
      int gg = gp ^ ((brow >> 1) & 3);
      int lb = __builtin_amdgcn_readfirstlane(ub);
      async_copy16((const void*)(Wouthi + (size_t)brow * 128 + kb + gg * 8), (void*)(Bh + lb * 8));
      async_copy16((const void*)(Woutlo + (size_t)brow * 128 + kb + gg * 8), (void*)(Bl + lb * 8));
    }
    __syncthreads();
    short8 ah[2], al[2], bh[2], blv[2];
#pragma unroll
    for (int i = 0; i < 2; ++i) {
      int arow = wm + i * 16 + l15;
      int g16 = c * 4 + quad;
      int slot = arow * 16 + (g16 ^ (arow & 15));
      ah[i] = *(const short8*)(AactH + slot * 8);
      al[i] = *(const short8*)(AactL + slot * 8);
    }
#pragma unroll
    for (int j = 0; j < 2; ++j) {
      int n = wn3 + j * 16 + l15;
      int slot = n * 4 + (quad ^ ((n >> 1) & 3));
      bh[j] = *(const short8*)(Bh + slot * 8);
      blv[j] = *(const short8*)(Bl + slot * 8);
    }
#pragma unroll
    for (int i = 0; i < 2; ++i)
#pragma unroll
      for (int j = 0; j < 2; ++j) {
        acc[i][j] = __builtin_amdgcn_mfma_f32_16x16x32_bf16(ah[i], bh[j], acc[i][j], 0, 0, 0);
        acc[i][j] = __builtin_amdgcn_mfma_f32_16x16x32_bf16(ah[i], blv[j], acc[i][j], 0, 0, 0);
        acc[i][j] = __builtin_amdgcn_mfma_f32_16x16x32_bf16(al[i], bh[j], acc[i][j], 0, 0, 0);
      }
    __syncthreads();
  }
#pragma unroll
  for (int i = 0; i < 2; ++i)
#pragma unroll
    for (int r = 0; r < 4; ++r) {
      int m = m0 + wm + i * 16 + quad * 4 + r;
      if (m < M) {
#pragma unroll
        for (int j = 0; j < 2; ++j) {
          int n = wn3 + j * 16 + l15;
          P[(size_t)m * NOUT + n] = acc[i][j][r];
        }
      }
    }
}

// ---------------- MFMA fused edge block: 64-edge tile, 6 blocks/CU ----------------
// Tile: 64 edges x 128 cols, K=384 in 6 chunks of 64. XCD-contiguous block swizzle.
__global__ __launch_bounds__(256, 6) void k_edge_mfma(
    const ushort* __restrict__ hbf,    // [N][128] bf16
    const ushort* __restrict__ rbfh,   // [E][128] bf16 (sorted)
    const ushort* __restrict__ Wlbf,   // [128][384] bf16
    const float* __restrict__ bl,      // [128]
    const float* __restrict__ rbfG,    // [E][6] (sorted)
    const float* __restrict__ Wrbf,    // [128][6]
    const int* __restrict__ ssrc, const int* __restrict__ sdst,
    float* __restrict__ node,          // [N,128]
    int E, int nb, int perXcd) {
  __shared__ alignas(16) ushort ABs[64 * 64 + 128 * 64];  // As|Bs; epilogue alias fp32 redS[64][65]
  __shared__ float rbfS[64][6];
  __shared__ int dstS[64];
  __shared__ int srcS[64];

  // XCD-contiguous swizzle: HW round-robins blocks over 8 XCDs; give each XCD
  // a contiguous logical range so sorted-dst gathers stay in its L2.
  const int bp = blockIdx.x;
  const int lb = (bp & 7) * perXcd + (bp >> 3);
  if (lb >= nb) return;

  ushort* As = ABs;
  ushort* Bs = ABs + 64 * 64;

  const int tid = threadIdx.x;
  const int e0 = lb * 64;

  if (tid < 64) {
    int e = min(e0 + tid, E - 1);
    dstS[tid] = sdst[e];
    srcS[tid] = ssrc[e];
  }
  for (int idx = tid; idx < 64 * NR; idx += 256) {
    int gidx = e0 * NR + idx;
    ((float*)rbfS)[idx] = (gidx < E * NR) ? rbfG[gidx] : 0.f;
  }
  __syncthreads();

  const int w = tid >> 6;
  const int lane = tid & 63;
  const int l15 = lane & 15, quad = lane >> 4;
  const int wm = (w >> 1) * 32;   // edge strip: 0 or 32
  const int wn = (w & 1) * 64;    // col strip: 0 or 64

  floatx4 acc[2][4];
#pragma unroll
  for (int i = 0; i < 2; ++i)
#pragma unroll
    for (int j = 0; j < 4; ++j) acc[i][j] = floatx4{0.f, 0.f, 0.f, 0.f};

  const int Em1 = E - 1;

  for (int c = 0; c < 6; ++c) {
    // A tile: 512 slots, wave covers 128 (2 issues)
    {
      const int* rowS = (c < 2) ? dstS : ((c < 4) ? srcS : nullptr);
      const ushort* base = (c < 4) ? hbf : rbfh;
      const int off = (c & 1) * 64;
#pragma unroll
      for (int i = 0; i < 2; ++i) {
        int u = w * 128 + i * 64 + lane;
        int nrow = u >> 3, gp = u & 7;
        int g = gp ^ (nrow & 7);
        int row = rowS ? rowS[nrow] : min(e0 + nrow, Em1);
        const ushort* gsrc = base + (size_t)row * H + off + g * 8;
        int lbo = __builtin_amdgcn_readfirstlane(w * 128 + i * 64);
        async_copy16((const void*)gsrc, (void*)(As + lbo * 8));
      }
    }
    // B tile: 1024 slots, wave covers 256 (4 issues)
    {
#pragma unroll
      for (int i = 0; i < 4; ++i) {
        int u = w * 256 + i * 64 + lane;
        int nrow = u >> 3, gp = u & 7;
        int g = gp ^ (nrow & 7);
        const ushort* gsrc = Wlbf + (size_t)nrow * 384 + c * 64 + g * 8;
        int lbo = __builtin_amdgcn_readfirstlane(w * 256 + i * 64);
        async_copy16((const void*)gsrc, (void*)(Bs + lbo * 8));
      }
    }
    __syncthreads();
#pragma unroll
    for (int s = 0; s < 2; ++s) {
      const int gg = s * 4 + quad;
      short8 af[2], bfr[4];
#pragma unroll
      for (int i = 0; i < 2; ++i) {
        int m = wm + i * 16 + l15;
        af[i] = *(const short8*)(As + (m * 8 + (gg ^ (m & 7))) * 8);
      }
#pragma unroll
      for (int j = 0; j < 4; ++j) {
        int n = wn + j * 16 + l15;
        bfr[j] = *(const short8*)(Bs + (n * 8 + (gg ^ (n & 7))) * 8);
      }
#pragma unroll
      for (int i = 0; i < 2; ++i)
#pragma unroll
        for (int j = 0; j < 4; ++j)
          acc[i][j] = __builtin_amdgcn_mfma_f32_16x16x32_bf16(af[i], bfr[j], acc[i][j], 0, 0, 0);
    }
    __syncthreads();
  }

  // ---- epilogue (R5 style): t = swish(z+bl) * (rbf . Wrbf[n]); segmented sum ----
  float* redS = (float*)ABs;   // [64][65]
  float wt[4][NR], blv[4];
#pragma unroll
  for (int j = 0; j < 4; ++j) {
    int n = wn + j * 16 + l15;
    blv[j] = bl[n];
#pragma unroll
    for (int r = 0; r < NR; ++r) wt[j][r] = Wrbf[n * NR + r];
  }

  for (int half = 0; half < 2; ++half) {
    __syncthreads();
    if ((w & 1) == half) {
#pragma unroll
      for (int i = 0; i < 2; ++i)
#pragma unroll
        for (int r = 0; r < 4; ++r) {
          int m = wm + i * 16 + quad * 4 + r;
          float rb[NR];
#pragma unroll
          for (int q = 0; q < NR; ++q) rb[q] = rbfS[m][q];
#pragma unroll
          for (int j = 0; j < 4; ++j) {
            float z = acc[i][j][r] + blv[j];
            float ev = swishf(z);
            float wv = 0.f;
#pragma unroll
            for (int q = 0; q < NR; ++q) wv += rb[q] * wt[j][q];
            redS[m * 65 + j * 16 + l15] = ev * wv;  // zero when e>=E (rb==0)
          }
        }
    }
    __syncthreads();
    int cc = tid & 63, chunk = tid >> 6;
    int mstart = chunk * 16;
    float s = 0.f;
    int prev = dstS[mstart];
    for (int m = mstart; m < mstart + 16; ++m) {
      int d = dstS[m];
      float v = redS[m * 65 + cc];
      if (d != prev) {
        atomicAdd(&node[(size_t)prev * H + half * 64 + cc], s);
        s = 0.f;
        prev = d;
      }
      s += v;
    }
    atomicAdd(&node[(size_t)prev * H + half * 64 + cc], s);
  }
}

extern "C" void kernel_launch(void* const* d_in, const int* in_sizes, int n_in,
                              void* d_out, int out_size, void* d_ws, size_t ws_size,
                              hipStream_t stream) {
  const float* x    = (const float*)d_in[0];
  const float* pos  = (const float*)d_in[1];
  const float* freq = (const float*)d_in[2];
  const float* Wx   = (const float*)d_in[3];
  const float* Wr   = (const float*)d_in[4];
  const float* br   = (const float*)d_in[5];
  const float* Wl   = (const float*)d_in[6];
  const float* bl   = (const float*)d_in[7];
  const float* Wrbf = (const float*)d_in[8];
  const float* Wls  = (const float*)d_in[9];
  const float* bls  = (const float*)d_in[10];
  const float* Wout = (const float*)d_in[11];
  const int* esrc = (const int*)d_in[12];
  const int* edst = (const int*)d_in[13];
  const int* ii   = (const int*)d_in[14];
  const int* jjv  = (const int*)d_in[15];
  const int* kkv  = (const int*)d_in[16];

  const int N = in_sizes[0] / H;
  const int E = in_sizes[12];
  const int T = in_sizes[14];

  float* out   = (float*)d_out;
  float* P     = out;                       // [N,64]
  float* angle = out + (size_t)N * NOUT;    // [T]

  float* ws = (float*)d_ws;
  float* rbfG  = ws; ws += (size_t)E * NR;
  float* nodeA = ws; ws += (size_t)N * H;
  ushort* u = (ushort*)ws;
  ushort* hbf    = u; u += (size_t)N * H;
  ushort* Wlbf   = u; u += 3 * H * H;
  ushort* rbfh   = u; u += (size_t)E * H;
  ushort* Wxhi   = u; u += H * H;
  ushort* Wxlo   = u; u += H * H;
  ushort* Wlshi  = u; u += 3 * H * H;
  ushort* Wlslo  = u; u += 3 * H * H;
  ushort* Wouthi = u; u += NOUT * H;
  ushort* Woutlo = u; u += NOUT * H;
  int* ip = (int*)u;
  int* cnt   = ip; ip += N;
  int* cur   = ip; ip += N;
  int* perm  = ip; ip += E;
  int* ssrcA = ip; ip += E;
  int* sdstA = ip; ip += E;

  // zeros (nodeA + cnt)
  {
    int n4 = N * H / 4;
    k_zeroinit<<<(n4 + 255) / 256, 256, 0, stream>>>((float4*)nodeA, n4, cnt, N);
  }

  // counting sort of edges by dst
  k_hist<<<(E + 255) / 256, 256, 0, stream>>>(edst, cnt, E);
  k_scan<<<1, 1024, 0, stream>>>(cnt, cur, N);
  k_scatter<<<(E + 255) / 256, 256, 0, stream>>>(edst, cur, perm, E);

  // merged weight converts/splits
  k_prep<<<(122880 + 255) / 256, 256, 0, stream>>>(Wl, Wx, Wls, Wout, Wlbf,
                                                   Wxhi, Wxlo, Wlshi, Wlslo, Wouthi, Woutlo);

  // per-edge features in sorted order; angles
  k_edge_feat<<<(E + 63) / 64, 256, 0, stream>>>(pos, esrc, edst, freq, Wr, br, perm,
                                                 rbfG, rbfh, ssrcA, sdstA, E);
  if (T > 0)
    k_angle<<<(T + 255) / 256, 256, 0, stream>>>(pos, ii, jjv, kkv, angle, T);

  // h = x @ Wx^T -> bf16
  k_gemm_split<128, false, false, true><<<(N + 63) / 64, 256, 0, stream>>>(
      x, Wxhi, Wxlo, nullptr, hbf, N);

  // fused MFMA edge block (64-edge tiles, XCD swizzle) -> segmented sum into nodeA
  {
    int nb = (E + 63) / 64;
    int perXcd = (nb + 7) / 8;
    int grid = perXcd * 8;
    k_edge_mfma<<<grid, 256, 0, stream>>>(hbf, rbfh, Wlbf, bl, rbfG, Wrbf,
                                          ssrcA, sdstA, nodeA, E, nb, perXcd);
  }

  // fused node MLP
  k_node_mlp<<<(N + 63) / 64, 256, 0, stream>>>(nodeA, Wlshi, Wlslo, Wouthi, Woutlo,
                                                bls, P, N);
}